// Round 15
// baseline (241.449 us; speedup 1.0000x reference)
//
#include <hip/hip_runtime.h>
#include <math.h>

#define PI_D 3.14159265358979323846

#define BATCH 128
#define F1 20
#define F2 40
#define FOUT 10
#define NS1 100   // sum_{l<10} (2l+1)
#define NS2 286   // sum_{l<6} (2l+1)^2
#define NH2 146   // Hermitian half count of NS2

typedef float v2f __attribute__((ext_vector_type(2)));
#define PKFMA(a,b,c) __builtin_elementwise_fma((a),(b),(c))
#define SW(v) __builtin_shufflevector((v),(v),1,0)
static __device__ __forceinline__ v2f bc2(float s){ return (v2f){s,s}; }
static __device__ __forceinline__ v2f ldv(const float2* p){ return *(const v2f*)p; }

// async global->LDS, 16B per lane; lds arg must be wave-uniform base
#define GLOAD_LDS16(g,l) __builtin_amdgcn_global_load_lds( \
  (const __attribute__((address_space(1))) void*)(g), \
  (__attribute__((address_space(3))) void*)(l), 16, 0, 0)

__constant__ int ZB10c[11] = {0,1,10,35,84,165,286,455,680,969,1330};
__constant__ int B2OFFc[7] = {0,1,10,35,84,165,286};
__constant__ int HOFFc[7]  = {0,1,6,19,44,85,146};
// E8c[q] = exp(-2*pi*i*q/8)
__constant__ float2 E8c[8] = {
  { 1.f, 0.f}, { 0.70710678118654752f,-0.70710678118654752f},
  { 0.f,-1.f}, {-0.70710678118654752f,-0.70710678118654752f},
  {-1.f, 0.f}, {-0.70710678118654752f, 0.70710678118654752f},
  { 0.f, 1.f}, { 0.70710678118654752f, 0.70710678118654752f}};

// wave-synchronous phase fence
#define WFENCE do{ __builtin_amdgcn_sched_barrier(0); \
  asm volatile("s_waitcnt lgkmcnt(0)" ::: "memory"); \
  __builtin_amdgcn_sched_barrier(0); }while(0)

// half-space H = { (m,n): n>0 } U { (m,n): n==0 && m>=0 }
__device__ inline void h_decode(int h, int& l, int& m, int& n){
  l=0; while(HOFFc[l+1]<=h) ++l;
  int r=h-HOFFc[l], L=2*l+1;
  if(r<l+1){ n=0; m=r; }
  else { int q=r-(l+1); n=q/L+1; m=q%L-l; }
}

// ---------------- double-precision table generation helpers ----------------
__device__ inline double ipow_d(double x, int n){ double r=1.0; for(int i=0;i<n;++i) r*=x; return r; }

// wigd with factorial table (values identical to iterative dfact)
__device__ double wigd_t(int l, int mp, int m, double beta, const double* F){
  double cb=cos(0.5*beta), sb=sin(0.5*beta);
  double pref=sqrt(F[l+mp]*F[l-mp]*F[l+m]*F[l-m]);
  int s0 = (m-mp>0) ? (m-mp) : 0;
  int s1 = (l+m < l-mp) ? (l+m) : (l-mp);
  double acc=0.0;
  for(int s=s0;s<=s1;++s){
    double den=F[l+m-s]*F[s]*F[mp-m+s]*F[l-mp-s];
    double t=ipow_d(cb,2*l+m-mp-2*s)*ipow_d(sb,mp-m+2*s)/den;
    acc += ((mp-m+s)&1)? -t : t;
  }
  return pref*acc;
}

__device__ double dhw(int b, int j){
  double beta=PI_D*(2*j+1)/(4.0*b);
  double s=0.0;
  for(int k=0;k<b;++k) s += sin((2*k+1)*beta)/(2*k+1);
  return (2.0/b)*sin(beta)*s;
}

// ---------------- single merged table-generation kernel (+KA) ----------------
// beta->pi-beta symmetry: d^l_{m',m}(pi-b) = (-1)^{l+m} d^l_{-m',m}(b)
__global__ void gen_all(const float* __restrict__ k2,
                        float* A1, float* D1SJ, float* W3H, float* D2SJ,
                        float* D3_2, float* D3_1, float* WINT,
                        float2* E60, float2* E20, float2* E12,
                        unsigned* zLUT, unsigned* xh2LUT, unsigned* h2LUT,
                        unsigned short* fhLUT, unsigned* aLUT,
                        float2* KA){
  __shared__ double factS[21];
  __shared__ double dhwS[60];
  __shared__ float2 E8L[8];
  int blk=blockIdx.x, t=threadIdx.x;
  if(t==0){ double f=1.0; factS[0]=1.0; for(int k=1;k<=20;++k){ f*=(double)k; factS[k]=f; } }
  if(blk<24){ if(t<60) dhwS[t]=dhw(30,t); }
  else if(blk>=76 && blk<82){ if(t<20) dhwS[t]=dhw(10,t); }
  if(t<8) E8L[t]=E8c[t];
  __syncthreads();
  const double* F=factS;
  if(blk<24){                     // A1: [j][s1], 60x100
    int idx=blk*256+t;
    if(idx<6000){
      int j=idx/NS1, s=idx%NS1;
      int l=0; while((l+1)*(l+1)<=s) ++l;
      int m=s-l*l-l;
      double beta=PI_D*(2*j+1)/120.0;
      A1[idx]=(float)(wigd_t(l,m,0,beta,F)*dhwS[j]*(2.0*PI_D/60.0));
    }
  } else if(blk<76){              // D1SJ: j=0..9 computed, 19-j derived
    int idx=(blk-24)*256+t; if(idx>=13300) return;
    int j=idx/1330, s=idx%1330;
    int l=0; while(ZB10c[l+1]<=s) ++l;
    int r=s-ZB10c[l]; int L=2*l+1;
    int mi=r/L, ni=r%L;
    double beta=PI_D*(2*j+1)/40.0;
    float v=(float)((2*l+1)*wigd_t(l,mi-l,ni-l,beta,F));
    D1SJ[j*1330+s]=v;
    int s2=ZB10c[l]+(2*l-mi)*L+ni;
    D1SJ[(19-j)*1330+s2]=(ni&1)? -v : v;
  } else if(blk<82){              // W3H: j=0..9 computed, 19-j derived
    int idx=(blk-76)*256+t;
    if(idx<10*NH2){
      int j=idx/NH2, h=idx%NH2;
      int l,m,n; h_decode(h,l,m,n);
      double beta=PI_D*(2*j+1)/40.0;
      double c=2.0*PI_D/20.0;
      float v=(float)(wigd_t(l,m,n,beta,F)*dhwS[j]*c*c);
      W3H[j*NH2+h]=v;
      if(n==0){
        W3H[(19-j)*NH2+h]=((l+m)&1)? -v : v;
      } else {
        int L=2*l+1;
        int hp=HOFFc[l]+(l+1)+(n-1)*L+(l-m);   // (m,n) -> (-m,n)
        W3H[(19-j)*NH2+hp]=((l+n)&1)? -v : v;
      }
    }
  } else if(blk<89){              // D2SJ: j=0..5 computed, 11-j derived
    int idx=(blk-82)*256+t; if(idx>=1716) return;
    int j=idx/286, s=idx%286;
    int l=0; while(B2OFFc[l+1]<=s) ++l;
    int r=s-B2OFFc[l]; int L=2*l+1;
    int mi=r/L, ni=r%L;
    double beta=PI_D*(2*j+1)/24.0;
    float v=(float)((2*l+1)*wigd_t(l,mi-l,ni-l,beta,F));
    D2SJ[j*286+s]=v;
    int s2=B2OFFc[l]+(2*l-mi)*L+ni;
    D2SJ[(11-j)*286+s2]=(ni&1)? -v : v;
  } else if(blk<93){              // D3_2: [bi][286]
    int idx=(blk-89)*256+t; if(idx>=3*286) return;
    int bi=idx/286, s=idx%286;
    int l=0; while(B2OFFc[l+1]<=s) ++l;
    int r=s-B2OFFc[l]; int L=2*l+1;
    int mi=r/L, ni=r%L;
    double beta=(bi+1)*(PI_D/8.0)/3.0;
    D3_2[idx]=(float)wigd_t(l,mi-l,ni-l,beta,F);
  } else if(blk<95){              // D3_1: [bi][100]
    int idx=(blk-93)*256+t; if(idx>=3*100) return;
    int bi=idx/100, s=idx%100;
    int l=0; while((l+1)*(l+1)<=s) ++l;
    int m=s-l*l-l;
    double beta=(bi+1)*(PI_D/8.0)/3.0;
    D3_1[idx]=(float)wigd_t(l,m,0,beta,F);
  } else if(blk==95){             // misc
    if(t<12){ double c=2.0*PI_D/12.0; WINT[t]=(float)(dhw(6,t)*c*c); }
    if(t<60){ double a=2.0*PI_D*t/60.0; E60[t]=make_float2((float)cos(a),(float)sin(a)); }
    if(t<20){ double a=2.0*PI_D*t/20.0; E20[t]=make_float2((float)cos(a),(float)sin(a)); }
    if(t<12){ double a=2.0*PI_D*t/12.0; E12[t]=make_float2((float)cos(a),(float)sin(a)); }
  } else if(blk<102){             // zLUT[1330]: packed s1x | s1k<<16
    int idx=(blk-96)*256+t; if(idx>=1330) return;
    int l=0; while(ZB10c[l+1]<=idx) ++l;
    int r=idx-ZB10c[l], L=2*l+1;
    int mi=r/L, ni=r%L;
    unsigned s1x=(unsigned)(l*l+mi), s1k=(unsigned)(l*l+ni);
    zLUT[idx]=s1x|(s1k<<16);
  } else if(blk==102){            // xh2LUT, h2LUT, fhLUT
    if(t<146){
      int l,m,n; h_decode(t,l,m,n);
      int L=2*l+1;
      int s2 =B2OFFc[l]+(m+l)*L+(n+l);
      int s2p=B2OFFc[l]+(l-m)*L+(l-n);
      unsigned sg=(unsigned)((m+n)&1);
      xh2LUT[t]=(unsigned)s2 | ((unsigned)s2p<<10) | (sg<<20);
      h2LUT[t]=(unsigned)l | ((unsigned)(m+l)<<4) | ((unsigned)(n+l)<<8) | ((unsigned)s2<<12);
      fhLUT[t]=(unsigned short)((n==0)? m : 6+(n-1)*11+(m+5));
    }
  } else if(blk==103){            // aLUT[181] sorted by lmin
    if(t==0){
      int idx=0;
      for(int lm=0;lm<10;++lm){
        for(int m=0;m<10;++m){
          int nlo=(m==0)?0:-9;
          for(int n=nlo;n<10;++n){
            int an=n<0?-n:n;
            int lmin=m>an?m:an;
            if(lmin!=lm) continue;
            int L=2*lm+1;
            int zi=ZB10c[lm]+(m+lm)*L+(n+lm);
            aLUT[idx++]=(unsigned)zi | ((unsigned)m<<11) | ((unsigned)(n+9)<<15) | ((unsigned)lm<<20);
          }
        }
      }
    }
  } else {                        // blk 104..703: KA (k2 gamma-DFT)
    int idx=(blk-104)*256+t;
    if(idx<153600){
      int ai=idx&7, q=(idx>>3)&7;
      int r2=idx>>6;
      int bi=r2%3, io=r2/3;
      const float* kp=k2+(size_t)io*192+bi*64+ai*8;
      v2f acc={0.f,0.f};
      int ph=0;
      #pragma unroll
      for(int gi=0;gi<8;++gi){
        acc=PKFMA(bc2(kp[gi]), ldv(&E8L[ph]), acc);
        ph=(ph+q)&7;
      }
      KA[(size_t)io*192+bi*64+q*8+ai]=make_float2(acc.x,acc.y);
    }
  }
}

// ---------------- front: per-b DFT+S2 analysis | k1h ----------------
__global__ __launch_bounds__(256) void front_k(const float* __restrict__ x,
    const float* __restrict__ k1,
    const float2* __restrict__ E60, const float* __restrict__ A1,
    const float* __restrict__ D3_1,
    float2* __restrict__ XHAT, float2* __restrict__ K1H){
  int blk=blockIdx.x, t=threadIdx.x;
  if(blk<128){
    __shared__ __align__(16) float xs[3600];
    __shared__ float2 E60s[60];      // conjugated twiddles
    __shared__ float2 XFs[1140];     // [j][mi], mi = m+9
    if(t<60){ float2 e=E60[t]; E60s[t]=make_float2(e.x,-e.y); }
    {
      const float4* src=(const float4*)(x+blk*3600);
      float4* dst=(float4*)xs;
      for(int i=t;i<900;i+=256) GLOAD_LDS16(src+i, dst+(i&~63));
    }
    __syncthreads();
    // radix-2: x(a)+/-x(a+30) with e^{-im(a+30)} = (-1)^m e^{-ima}
    for(int idx=t; idx<1140; idx+=256){
      int j=idx/19, mi=idx%19;
      int step=(mi<9)? mi+51 : mi-9;
      bool modd = ((mi&1)==0);       // parity(mi-9) = !parity(mi)
      const float* xr=xs+j*60;
      v2f acc={0.f,0.f};
      int k=0;
      for(int a=0;a<30;++a){
        float xv = modd ? (xr[a]-xr[a+30]) : (xr[a]+xr[a+30]);
        acc=PKFMA(bc2(xv), ldv(&E60s[k]), acc);
        k+=step; if(k>=60)k-=60;
      }
      XFs[idx]=make_float2(acc.x,acc.y);
    }
    __syncthreads();
    for(int s=t; s<100; s+=256){
      int l=0; while((l+1)*(l+1)<=s) ++l;
      int m=s-l*l-l;
      const float2* xf=&XFs[m+9];
      v2f acc={0.f,0.f};
      for(int j=0;j<60;++j){
        acc=PKFMA(bc2(A1[j*NS1+s]), ldv(&xf[j*19]), acc);
      }
      XHAT[blk*NS1+s]=make_float2(acc.x,acc.y);
    }
  } else {
    __shared__ float2 E8s[8];
    if(t<8) E8s[t]=E8c[t];
    __syncthreads();
    int idx=(blk-128)*256+t;
    if(idx<F1*NS1){
      int o=idx/NS1, s=idx%NS1;
      int l=0; while((l+1)*(l+1)<=s) ++l;
      int m=s-l*l-l;
      int mm=m&7;
      v2f acc={0.f,0.f};
      for(int bi=0;bi<3;++bi){
        v2f sum={0.f,0.f};
        int q=0;
        #pragma unroll
        for(int ai=0;ai<8;++ai){
          sum=PKFMA(bc2(k1[o*24+bi*8+ai]), ldv(&E8s[q]), sum);
          q=(q+mm)&7;
        }
        acc=PKFMA(bc2(D3_1[bi*100+s]), sum, acc);
      }
      const float SC1f = 0.06123724356957945f;
      K1H[idx]=make_float2(acc.x*SC1f, acc.y*SC1f);
    }
  }
}

// fused1: 8-wave wave-per-j barrier-free pipeline, packed-fp32 + radix-2.
// XH2 layout: [b][F1][286]
__global__ __launch_bounds__(512,6) void fused1(
    const float2* __restrict__ XHAT, const float2* __restrict__ K1H,
    const float* __restrict__ D1SJ, const float* __restrict__ W3H,
    const float2* __restrict__ E20, const float* __restrict__ bias1,
    const unsigned* __restrict__ zLUT, const unsigned* __restrict__ xh2LUT,
    const unsigned short* __restrict__ fhLUT, const unsigned* __restrict__ aLUT,
    float2* __restrict__ XH2){
  const int b=blockIdx.x, o=blockIdx.y, t=threadIdx.x;
  const int ln=t&63, w=t>>6;
  __shared__ __align__(16) float2 zS[1330];
  __shared__ __align__(16) float2 TWE2[400];  // [r][k] = e^{i r k th}, 20x20
  __shared__ __align__(16) float2 regA[8][200];
  __shared__ __align__(16) float2 regB[8][190];

  for(int idx=t; idx<400; idx+=512){
    int r=idx/20, c=idx%20;
    TWE2[idx]=E20[(r*c)%20];
  }
  {
    float2* st=regA[0];   // xh rows staged: [0..99]=XHAT row, [100..199]=K1H row
    if(t<100) st[t]=XHAT[b*NS1+t];
    else if(t<200) st[t]=K1H[o*NS1+(t-100)];
  }
  __syncthreads();
  {
    const float2* st=regA[0];
    for(int idx=t; idx<1330; idx+=512){
      unsigned u=zLUT[idx];
      v2f xa=ldv(&st[u&0xffff]);
      v2f kb=ldv(&st[100+(u>>16)]);
      v2f p1=xa*kb, p2=xa*SW(kb);
      zS[idx]=make_float2(p1.x+p1.y, p2.y-p2.x);   // xa*conj(kb)
    }
  }
  __syncthreads();

  const float bb1=bias1[o];
  float2* G  = regA[w];
  float*  vbF= (float*)regA[w];
  float2* Fq = regA[w];
  float*  RB = (float*)regB[w];   // Sx[0..180) Sy[180..360) T0[360..380)
  float*  Sx = RB;
  float*  Sy = RB+180;
  float*  T0f= RB+360;
  float2* U_T= regB[w];           // reuse after C
  v2f fa0={0.f,0.f}, fa1=fa0, fa2=fa0;

  // B-phase twiddle rows: n=c-9 -> row (c+11)%20
  const int BROW[19]={11,12,13,14,15,16,17,18,19,0,1,2,3,4,5,6,7,8,9};

  for(int jq=0;jq<3;++jq){
    const int j=jq*8+w;
    const bool act=(j<20);
    const float* Dg=D1SJ + (act? j*1330 : 0);
    // A: Wigner-beta contraction, half-space (181 items, lmin-sorted LUT)
    if(act) for(int idx=ln; idx<181; idx+=64){
      unsigned au=aLUT[idx];
      int zi=au&2047;
      int m=(au>>11)&15, n9=(au>>15)&31, l=(au>>20)&15;
      int L=2*l+1;
      int m2=2*m+2;
      v2f a0={0.f,0.f};
      for(; l<10; ++l){
        a0=PKFMA(ldv(&zS[zi]), bc2(Dg[zi]), a0);
        zi += L*L + 2*L + m2; L += 2;
      }
      *(v2f*)&G[m*19+n9]=a0;
    }
    WFENCE;
    // B: radix-2 split S_m(g)/S_m(g+10): 45 items (mb x g-pair) + T0 (5 items)
    if(act){
    if(ln<45){
      int mb=ln/5+1, gp=(ln%5)*2;
      const float2* Gr=&G[mb*19];
      v2f E1a={0.f,0.f},E2a=E1a,O1a=E1a,O2a=E1a;
      v2f E1b=E1a,E2b=E1a,O1b=E1a,O2b=E1a;
      #pragma unroll
      for(int c=0;c<19;++c){
        v2f gv=ldv(&Gr[c]);
        const float* er=(const float*)&TWE2[BROW[c]*20+gp];
        float4 e01=*(const float4*)er;
        v2f e0={e01.x,e01.y}, e1={e01.z,e01.w};
        if(c&1){   // c odd -> n=c-9 even -> E
          E1a=PKFMA(gv,e0,E1a); E2a=PKFMA(gv,SW(e0),E2a);
          E1b=PKFMA(gv,e1,E1b); E2b=PKFMA(gv,SW(e1),E2b);
        } else {   // n odd -> O
          O1a=PKFMA(gv,e0,O1a); O2a=PKFMA(gv,SW(e0),O2a);
          O1b=PKFMA(gv,e1,O1b); O2b=PKFMA(gv,SW(e1),O2b);
        }
      }
      int si=(mb-1)*20+gp;
      float exa=E1a.x-E1a.y, oxa=O1a.x-O1a.y;
      float eya=E2a.x+E2a.y, oya=O2a.x+O2a.y;
      float exb=E1b.x-E1b.y, oxb=O1b.x-O1b.y;
      float eyb=E2b.x+E2b.y, oyb=O2b.x+O2b.y;
      *(v2f*)&Sx[si]   =(v2f){2.f*(exa+oxa), 2.f*(exb+oxb)};
      *(v2f*)&Sx[si+10]=(v2f){2.f*(exa-oxa), 2.f*(exb-oxb)};
      *(v2f*)&Sy[si]   =(v2f){2.f*(eya+oya), 2.f*(eyb+oyb)};
      *(v2f*)&Sy[si+10]=(v2f){2.f*(eya-oya), 2.f*(eyb-oyb)};
    } else if(ln<50){
      int gt=(ln-45)*2;
      float g0x=G[9].x;
      float Ea=0.f,Eb=0.f,Oa=0.f,Ob=0.f;
      #pragma unroll
      for(int n=1;n<10;++n){
        float2 gv=G[9+n];
        const float* er=(const float*)&TWE2[n*20+gt];
        float4 e01=*(const float4*)er;
        float ra=gv.x*e01.x-gv.y*e01.y;
        float rb=gv.x*e01.z-gv.y*e01.w;
        if((n&1)==0){ Ea+=ra; Eb+=rb; } else { Oa+=ra; Ob+=rb; }
      }
      T0f[gt]   =g0x+2.f*(Ea+Oa);
      T0f[gt+1] =g0x+2.f*(Eb+Ob);
      T0f[gt+10]=g0x+2.f*(Ea-Oa);
      T0f[gt+11]=g0x+2.f*(Eb-Ob);
    }
    }
    WFENCE;
    // C: radix-2 split v(a,g)/v(a+10,g): 50 items (a=0..9 x 4-g), bias+relu
    if(act && ln<50){
      int a=ln/5, g0=(ln%5)*4;
      v2f i01={T0f[g0]+bb1, T0f[g0+1]+bb1};
      v2f i23={T0f[g0+2]+bb1, T0f[g0+3]+bb1};
      v2f P01={0.f,0.f},P23=P01,Q01=P01,Q23=P01;
      #pragma unroll
      for(int m=1;m<10;++m){
        float2 e=TWE2[a*20+m];
        v2f sx01=*(const v2f*)&Sx[(m-1)*20+g0];
        v2f sx23=*(const v2f*)&Sx[(m-1)*20+g0+2];
        v2f sy01=*(const v2f*)&Sy[(m-1)*20+g0];
        v2f sy23=*(const v2f*)&Sy[(m-1)*20+g0+2];
        if(m&1){
          Q01=PKFMA(bc2(e.x),sx01,Q01); Q01=PKFMA(bc2(-e.y),sy01,Q01);
          Q23=PKFMA(bc2(e.x),sx23,Q23); Q23=PKFMA(bc2(-e.y),sy23,Q23);
        } else {
          P01=PKFMA(bc2(e.x),sx01,P01); P01=PKFMA(bc2(-e.y),sy01,P01);
          P23=PKFMA(bc2(e.x),sx23,P23); P23=PKFMA(bc2(-e.y),sy23,P23);
        }
      }
      v2f z2={0.f,0.f};
      v2f vA01=i01+P01+Q01, vA23=i23+P23+Q23;
      v2f vB01=i01+P01-Q01, vB23=i23+P23-Q23;
      *(v2f*)&vbF[a*20+g0]       =__builtin_elementwise_max(vA01,z2);
      *(v2f*)&vbF[a*20+g0+2]     =__builtin_elementwise_max(vA23,z2);
      *(v2f*)&vbF[(a+10)*20+g0]  =__builtin_elementwise_max(vB01,z2);
      *(v2f*)&vbF[(a+10)*20+g0+2]=__builtin_elementwise_max(vB23,z2);
    }
    WFENCE;
    // D: radix-2 input split U_T[nu][a]=sum_{g<10}(v(a,g)+/-v(a,g+10))e^{-i nu g}
    if(act && ln<60){
      int a=ln/3, np=ln%3;
      int nu0=2*np, nu1=2*np+1;
      int r0=(np==0)?0:(20-2*np);
      int r1=19-2*np;
      const float* vp=&vbF[a*20];
      const float2* T0r=&TWE2[r0*20];
      const float2* T1r=&TWE2[r1*20];
      v2f u0={0.f,0.f}, u1=u0;
      #pragma unroll
      for(int g=0;g<10;++g){
        float va=vp[g], vb=vp[g+10];
        u0=PKFMA(bc2(va+vb), ldv(&T0r[g]), u0);
        u1=PKFMA(bc2(va-vb), ldv(&T1r[g]), u1);
      }
      *(v2f*)&U_T[nu0*20+a]=u0; *(v2f*)&U_T[nu1*20+a]=u1;
    }
    WFENCE;
    // E: radix-2 input split Fq(mu,nu)=sum_{a<10}(U[a]+/-U[a+10])e^{-i mu a}
    if(act && ln<61){
      int mu,nu;
      if(ln<6){ mu=ln; nu=0; } else { int q=ln-6; nu=q/11+1; mu=q%11-5; }
      int mm=(mu+20)%20;
      int rm=(20-mm)%20;
      bool modd=(mm&1);
      const float2* Ur=&U_T[nu*20];
      const float2* Er=&TWE2[rm*20];
      v2f p1={0.f,0.f}, p2=p1;
      #pragma unroll
      for(int a=0;a<10;++a){
        v2f ua=ldv(&Ur[a]), ub=ldv(&Ur[a+10]);
        v2f u = modd ? (ua-ub) : (ua+ub);
        v2f e=ldv(&Er[a]);
        p1=PKFMA(u,e,p1);
        p2=PKFMA(u,SW(e),p2);
      }
      Fq[ln]=make_float2(p1.x-p1.y, p2.x+p2.y);
    }
    WFENCE;
    // F: accumulate half-s2 with W3H into registers
    if(act){
      const float* W3r=W3H + j*NH2;
      fa0=PKFMA(bc2(W3r[ln]),    ldv(&Fq[fhLUT[ln]]),    fa0);
      fa1=PKFMA(bc2(W3r[64+ln]), ldv(&Fq[fhLUT[64+ln]]), fa1);
      if(ln<18) fa2=PKFMA(bc2(W3r[128+ln]), ldv(&Fq[fhLUT[128+ln]]), fa2);
    }
    WFENCE;
  }
  // spill register accumulators, merge 8 waves, expand half->full by conjugation
  regB[w][ln]=make_float2(fa0.x,fa0.y);
  regB[w][64+ln]=make_float2(fa1.x,fa1.y);
  if(ln<18) regB[w][128+ln]=make_float2(fa2.x,fa2.y);
  __syncthreads();
  float2* XHrow=XH2+(size_t)(b*F1+o)*286;
  for(int h=t; h<146; h+=512){
    unsigned u=xh2LUT[h];
    int s2=u&1023, s2p=(u>>10)&1023;
    float sg=((u>>20)&1)? -1.f : 1.f;
    float2 a0=regB[0][h], a1=regB[1][h], a2=regB[2][h], a3=regB[3][h];
    float2 a4=regB[4][h], a5=regB[5][h], a6=regB[6][h], a7=regB[7][h];
    float2 a=make_float2(a0.x+a1.x+a2.x+a3.x+a4.x+a5.x+a6.x+a7.x,
                         a0.y+a1.y+a2.y+a3.y+a4.y+a5.y+a6.y+a7.y);
    XHrow[s2 ]=a;
    XHrow[s2p]=make_float2(sg*a.x, -sg*a.y);
  }
}

// K2H: block per (i,o); KA row staged to LDS once; 146 h-threads consume.
// K2H layout: [o][F1][286]
__global__ __launch_bounds__(192) void k2h_k(const float2* __restrict__ KA,
                      const float* __restrict__ D3_2,
                      const unsigned* __restrict__ h2LUT, const unsigned* __restrict__ xh2LUT,
                      float2* __restrict__ K2H){
  __shared__ float2 kaS[192];
  __shared__ float2 E8s[8];
  int io=blockIdx.x, t=threadIdx.x;
  int i=io/F2, o=io%F2;
  if(t<8) E8s[t]=E8c[t];
  kaS[t]=KA[(size_t)io*192+t];
  __syncthreads();
  if(t>=146) return;
  unsigned hu=h2LUT[t];
  int l=hu&15, mi=(hu>>4)&15, ni=(hu>>8)&15, s2=hu>>12;
  int m=mi-l, n=ni-l;
  unsigned xu=xh2LUT[t];
  int s2p=(xu>>10)&1023;
  float sg=((xu>>20)&1)? -1.f : 1.f;
  int q=n&7, p=(m-n)&7;
  v2f a1={0.f,0.f}, a2=a1;
  for(int bi=0;bi<3;++bi){
    const float2* kp=&kaS[bi*64+q*8];
    v2f s1={0.f,0.f}, s2v=s1;
    int ph=0;
    #pragma unroll
    for(int ai=0;ai<8;++ai){
      v2f ka=ldv(&kp[ai]), e=ldv(&E8s[ph]);
      s1=PKFMA(ka,e,s1); s2v=PKFMA(ka,SW(e),s2v);
      ph=(ph+p)&7;
    }
    v2f dv=bc2(D3_2[bi*286+s2]);
    a1=PKFMA(dv,s1,a1); a2=PKFMA(dv,s2v,a2);
  }
  const float SC2f = 0.034722222222222224f;
  float re=(a1.x-a1.y)*SC2f, im=(a2.x+a2.y)*SC2f;
  float2* Krow=K2H+(size_t)(o*F1+i)*286;
  Krow[s2 ]=make_float2(re,im);
  Krow[s2p]=make_float2(sg*re,-sg*im);
}

// fused2: z2 build via i-half slab staging (GLOAD_LDS16, contiguous), then
// wave-per-3j single-pass synthesis+integrate with radix-2 B2
__global__ __launch_bounds__(256,3) void fused2(
    const float2* __restrict__ XH2, const float2* __restrict__ K2H,
    const float* __restrict__ D2SJ, const float* __restrict__ WINT,
    const float2* __restrict__ E12, const float* __restrict__ bias2,
    const unsigned* __restrict__ h2LUT, const unsigned* __restrict__ xh2LUT,
    float* __restrict__ FEAT){
  const int b=blockIdx.x, o=blockIdx.y, t=threadIdx.x;
  const int ln=t&63, w=t>>6;
  __shared__ __align__(16) float2 Xs[2860];   // [i=0..9][286]
  __shared__ __align__(16) float2 Ks[2860];
  __shared__ float2 zpS[572];                 // [hf][286]
  __shared__ float2 z2S[286];
  float* redS=(float*)zpS;                    // aliased: zpS dead after z2S merge
  float2* alias=(float2*)Xs;                  // reused after z-build
  float2* TWE12=alias;                        // [12][12]: e^{i r c th12}

  for(int hf=0; hf<2; ++hf){
    {
      const float4* xsrc=(const float4*)(XH2+(size_t)(b*F1+hf*10)*286);
      const float4* ksrc=(const float4*)(K2H+(size_t)(o*F1+hf*10)*286);
      float4* xd=(float4*)Xs; float4* kd=(float4*)Ks;
      for(int i4=t;i4<1430;i4+=256){
        int wb=i4&~63;
        GLOAD_LDS16(xsrc+i4, xd+wb);
        GLOAD_LDS16(ksrc+i4, kd+wb);
      }
    }
    __syncthreads();
    // z partial over this i-half: each item handles all 10 i's
    for(int h=t; h<146; h+=256){
      unsigned hu=h2LUT[h];
      int l=hu&15, mi=(hu>>4)&15, ni=(hu>>8)&15, s2=hu>>12;
      int L=2*l+1;
      int xr0=B2OFFc[l]+mi*L;
      int kr0=B2OFFc[l]+ni*L;
      v2f p1={0.f,0.f}, p2=p1;
      for(int i=0;i<10;++i){
        const float2* xp=Xs+i*286+xr0;
        const float2* kp=Ks+i*286+kr0;
        for(int k=0;k<L;++k){
          v2f xa=ldv(&xp[k]), kb=ldv(&kp[k]);
          p1=PKFMA(xa,kb,p1);
          p2=PKFMA(xa,SW(kb),p2);
        }
      }
      zpS[hf*286+h]=make_float2(p1.x+p1.y, p2.y-p2.x);  // indexed by h (compact)
    }
    __syncthreads();
  }
  // merge halves + Hermitian fill
  for(int h=t; h<146; h+=256){
    unsigned xu=xh2LUT[h];
    int s2=xu&1023, s2p=(xu>>10)&1023;
    float sg=((xu>>20)&1)? -1.f : 1.f;
    float2 pa=zpS[h], pb=zpS[286+h];
    float2 a=make_float2(pa.x+pb.x, pa.y+pb.y);
    z2S[s2]=a;
    z2S[s2p]=make_float2(sg*a.x,-sg*a.y);
  }
  __syncthreads();
  for(int idx=t; idx<144; idx+=256){
    int r=idx/12, c=idx%12;
    TWE12[idx]=E12[(r*c)%12];
  }
  __syncthreads();

  float2* base2=alias+144+w*400;
  float2* G2_0=base2; float2* G2_1=base2+66; float2* G2_2=base2+132;
  float*  SP=(float*)(base2+198);
  float*  S2x0=SP, *S2x1=SP+60, *S2x2=SP+120;
  float*  S2y0=SP+180, *S2y1=SP+240, *S2y2=SP+300;
  float*  T02=SP+360;               // [3][12]
  float personal=0.f;
  const float b2v=bias2[o];
  const int j0=3*w, j1=3*w+1, j2=3*w+2;
  const float* Dg0=D2SJ + j0*286;
  const float* Dg1=D2SJ + j1*286;
  const float* Dg2=D2SJ + j2*286;
  const int BR12[11]={7,8,9,10,11,0,1,2,3,4,5};

  // A2: 61 half items, 3 j's
  if(ln<61){
    int m,n;
    if(ln<6){m=0;n=ln;} else {int qq=ln-6;m=qq/11+1;n=qq%11-5;}
    int an=n<0?-n:n; int l=m>an?m:an; int L=2*l+1;
    int zi=B2OFFc[l]+(m+l)*L+(n+l); int m2=2*m+2;
    v2f a0={0.f,0.f}, a1=a0, a2=a0;
    for(;l<6;++l){
      v2f zv=ldv(&z2S[zi]);
      a0=PKFMA(zv, bc2(Dg0[zi]), a0);
      a1=PKFMA(zv, bc2(Dg1[zi]), a1);
      a2=PKFMA(zv, bc2(Dg2[zi]), a2);
      zi+=L*L+2*L+m2; L+=2;
    }
    int gi=m*11+(n+5);
    *(v2f*)&G2_0[gi]=a0; *(v2f*)&G2_1[gi]=a1; *(v2f*)&G2_2[gi]=a2;
  }
  WFENCE;
  // B2: radix-2 (g,g+6) split over n-parity: 30 items + 12 T0, 3 j's
  if(ln<30){
    int m=ln/6+1, g=ln%6;
    v2f E1_0={0.f,0.f},E2_0=E1_0,O1_0=E1_0,O2_0=E1_0;
    v2f E1_1=E1_0,E2_1=E1_0,O1_1=E1_0,O2_1=E1_0;
    v2f E1_2=E1_0,E2_2=E1_0,O1_2=E1_0,O2_2=E1_0;
    #pragma unroll
    for(int c=0;c<11;++c){
      float2 ef=TWE12[BR12[c]*12+g];
      v2f e={ef.x,ef.y};
      v2f g0=ldv(&G2_0[m*11+c]), g1=ldv(&G2_1[m*11+c]), g2=ldv(&G2_2[m*11+c]);
      if(c&1){  // n=c-5 even -> E
        E1_0=PKFMA(g0,e,E1_0); E2_0=PKFMA(g0,SW(e),E2_0);
        E1_1=PKFMA(g1,e,E1_1); E2_1=PKFMA(g1,SW(e),E2_1);
        E1_2=PKFMA(g2,e,E1_2); E2_2=PKFMA(g2,SW(e),E2_2);
      } else {  // n odd -> O
        O1_0=PKFMA(g0,e,O1_0); O2_0=PKFMA(g0,SW(e),O2_0);
        O1_1=PKFMA(g1,e,O1_1); O2_1=PKFMA(g1,SW(e),O2_1);
        O1_2=PKFMA(g2,e,O1_2); O2_2=PKFMA(g2,SW(e),O2_2);
      }
    }
    int si=(m-1)*12+g;
    {
      float Ex=E1_0.x-E1_0.y, Ox=O1_0.x-O1_0.y;
      float Ey=E2_0.x+E2_0.y, Oy=O2_0.x+O2_0.y;
      S2x0[si]=2.f*(Ex+Ox); S2x0[si+6]=2.f*(Ex-Ox);
      S2y0[si]=2.f*(Ey+Oy); S2y0[si+6]=2.f*(Ey-Oy);
    }
    {
      float Ex=E1_1.x-E1_1.y, Ox=O1_1.x-O1_1.y;
      float Ey=E2_1.x+E2_1.y, Oy=O2_1.x+O2_1.y;
      S2x1[si]=2.f*(Ex+Ox); S2x1[si+6]=2.f*(Ex-Ox);
      S2y1[si]=2.f*(Ey+Oy); S2y1[si+6]=2.f*(Ey-Oy);
    }
    {
      float Ex=E1_2.x-E1_2.y, Ox=O1_2.x-O1_2.y;
      float Ey=E2_2.x+E2_2.y, Oy=O2_2.x+O2_2.y;
      S2x2[si]=2.f*(Ex+Ox); S2x2[si+6]=2.f*(Ex-Ox);
      S2y2[si]=2.f*(Ey+Oy); S2y2[si+6]=2.f*(Ey-Oy);
    }
  } else if(ln<42){
    int g=ln-30;
    float r0=G2_0[5].x, r1=G2_1[5].x, r2=G2_2[5].x;
    #pragma unroll
    for(int n=1;n<6;++n){
      float2 e=TWE12[n*12+g];
      float2 g0=G2_0[5+n], g1=G2_1[5+n], g2=G2_2[5+n];
      r0+=2.f*(g0.x*e.x-g0.y*e.y);
      r1+=2.f*(g1.x*e.x-g1.y*e.y);
      r2+=2.f*(g2.x*e.x-g2.y*e.y);
    }
    T02[g]=r0; T02[12+g]=r1; T02[24+g]=r2;
  }
  WFENCE;
  // C2: 36 items, packed g-pairs, fused relu+integrate, 3 j's
  if(ln<36){
    float w0=WINT[j0], w1=WINT[j1], w2=WINT[j2];
    int a=ln/3, g4=(ln%3)*4;
    v2f iA0={T02[g4]+b2v, T02[g4+1]+b2v},       iB0={T02[g4+2]+b2v, T02[g4+3]+b2v};
    v2f iA1={T02[12+g4]+b2v, T02[12+g4+1]+b2v}, iB1={T02[12+g4+2]+b2v, T02[12+g4+3]+b2v};
    v2f iA2={T02[24+g4]+b2v, T02[24+g4+1]+b2v}, iB2={T02[24+g4+2]+b2v, T02[24+g4+3]+b2v};
    #pragma unroll
    for(int m=1;m<6;++m){
      float2 e=TWE12[a*12+m];
      v2f ex=bc2(e.x), eny=bc2(-e.y);
      int si=(m-1)*12+g4;
      v2f sx, sy;
      sx=*(const v2f*)&S2x0[si];   sy=*(const v2f*)&S2y0[si];
      iA0=PKFMA(ex,sx,iA0); iA0=PKFMA(eny,sy,iA0);
      sx=*(const v2f*)&S2x0[si+2]; sy=*(const v2f*)&S2y0[si+2];
      iB0=PKFMA(ex,sx,iB0); iB0=PKFMA(eny,sy,iB0);
      sx=*(const v2f*)&S2x1[si];   sy=*(const v2f*)&S2y1[si];
      iA1=PKFMA(ex,sx,iA1); iA1=PKFMA(eny,sy,iA1);
      sx=*(const v2f*)&S2x1[si+2]; sy=*(const v2f*)&S2y1[si+2];
      iB1=PKFMA(ex,sx,iB1); iB1=PKFMA(eny,sy,iB1);
      sx=*(const v2f*)&S2x2[si];   sy=*(const v2f*)&S2y2[si];
      iA2=PKFMA(ex,sx,iA2); iA2=PKFMA(eny,sy,iA2);
      sx=*(const v2f*)&S2x2[si+2]; sy=*(const v2f*)&S2y2[si+2];
      iB2=PKFMA(ex,sx,iB2); iB2=PKFMA(eny,sy,iB2);
    }
    v2f z2={0.f,0.f};
    v2f rA0=__builtin_elementwise_max(iA0,z2), rB0=__builtin_elementwise_max(iB0,z2);
    v2f rA1=__builtin_elementwise_max(iA1,z2), rB1=__builtin_elementwise_max(iB1,z2);
    v2f rA2=__builtin_elementwise_max(iA2,z2), rB2=__builtin_elementwise_max(iB2,z2);
    personal += w0*(rA0.x+rA0.y+rB0.x+rB0.y)
              + w1*(rA1.x+rA1.y+rB1.x+rB1.y)
              + w2*(rA2.x+rA2.y+rB2.x+rB2.y);
  }
  __syncthreads();
  redS[t]=personal;
  __syncthreads();
  for(int s=128;s>0;s>>=1){
    if(t<s) redS[t]+=redS[t+s];
    __syncthreads();
  }
  if(t==0) FEAT[b*F2+o]=redS[0];
}

__global__ void head_k(const float* __restrict__ FEAT, const float* __restrict__ w_out,
                       const float* __restrict__ b_lin, float* __restrict__ out){
  int idx=blockIdx.x*blockDim.x+threadIdx.x;
  if(idx>=BATCH*FOUT) return;
  int b=idx/FOUT, q=idx%FOUT;
  float acc=b_lin[q];
  for(int f=0;f<F2;++f) acc += FEAT[b*F2+f]*w_out[q*F2+f];
  out[idx]=acc;
}

extern "C" void kernel_launch(void* const* d_in, const int* in_sizes, int n_in,
                              void* d_out, int out_size, void* d_ws, size_t ws_size,
                              hipStream_t stream) {
  const float* x    =(const float*)d_in[0];
  const float* k1   =(const float*)d_in[1];
  const float* bias1=(const float*)d_in[2];
  const float* k2   =(const float*)d_in[3];
  const float* bias2=(const float*)d_in[4];
  const float* w_out=(const float*)d_in[5];
  const float* b_lin=(const float*)d_in[6];
  float* out=(float*)d_out;

  char* ws=(char*)d_ws;
  float*  A1   =(float* )(ws+0);        //  6000 f
  float*  D1SJ =(float* )(ws+24000);    //  26600 f
  float*  W3H  =(float* )(ws+130400);   //  2920 f
  float*  D2SJ =(float* )(ws+142080);   //  3432 f
  float*  D3_2 =(float* )(ws+155808);   //  858 f (+pad)
  float*  D3_1 =(float* )(ws+159248);   //  300 f
  float*  WINT =(float* )(ws+160448);   //  12 f
  float2* E60  =(float2*)(ws+160496);   //  60 c
  float2* E20  =(float2*)(ws+160976);   //  20 c
  float2* E12  =(float2*)(ws+161136);   //  12 c (+pad)
  unsigned* zLUT=(unsigned*)(ws+161248);//  1330 u32 (+pad)
  unsigned* xh2LUT=(unsigned*)(ws+166576); // 146 u32
  unsigned* h2LUT =(unsigned*)(ws+167160); // 146 u32
  unsigned short* fhLUT=(unsigned short*)(ws+167744); // 146 u16 (+pad)
  unsigned* aLUT =(unsigned*)(ws+168048);  // 181 u32 (+pad)
  float2* XHAT =(float2*)(ws+168784);   //  [b][100] c
  float2* K1H  =(float2*)(ws+271184);   //  [o][100] c
  float2* KA   =(float2*)(ws+287184);   //  153600 c (1.2MB)
  float2* XH2  =(float2*)(ws+1515984);  //  [b][F1][286] c
  float2* K2H  =(float2*)(ws+7373264);  //  [o][F1][286] c
  float*  FEAT =(float* )(ws+9203664);  //  128*40 f -> 9224144 total

  (void)in_sizes; (void)n_in; (void)out_size; (void)ws_size;

  gen_all<<<704,256,0,stream>>>(k2,A1,D1SJ,W3H,D2SJ,D3_2,D3_1,WINT,E60,E20,E12,
                                zLUT,xh2LUT,h2LUT,fhLUT,aLUT,KA);
  front_k<<<136,256,0,stream>>>(x,k1,E60,A1,D3_1,XHAT,K1H);
  dim3 g1(BATCH,F1);
  fused1<<<g1,512,0,stream>>>(XHAT,K1H,D1SJ,W3H,E20,bias1,zLUT,xh2LUT,fhLUT,aLUT,XH2);
  k2h_k<<<F1*F2,192,0,stream>>>(KA,D3_2,h2LUT,xh2LUT,K2H);
  dim3 g2(BATCH,F2);
  fused2<<<g2,256,0,stream>>>(XH2,K2H,D2SJ,WINT,E12,bias2,h2LUT,xh2LUT,FEAT);
  head_k<<<(BATCH*FOUT+255)/256,256,0,stream>>>(FEAT,w_out,b_lin,out);
}

// Round 16
// 202.723 us; speedup vs baseline: 1.1910x; 1.1910x over previous
//
#include <hip/hip_runtime.h>
#include <math.h>

#define PI_D 3.14159265358979323846

#define BATCH 128
#define F1 20
#define F2 40
#define FOUT 10
#define NS1 100   // sum_{l<10} (2l+1)
#define NS2 286   // sum_{l<6} (2l+1)^2
#define NH2 146   // Hermitian half count of NS2

typedef float v2f __attribute__((ext_vector_type(2)));
#define PKFMA(a,b,c) __builtin_elementwise_fma((a),(b),(c))
#define SW(v) __builtin_shufflevector((v),(v),1,0)
static __device__ __forceinline__ v2f bc2(float s){ return (v2f){s,s}; }
static __device__ __forceinline__ v2f ldv(const float2* p){ return *(const v2f*)p; }

// async global->LDS, 16B per lane; lds arg must be wave-uniform base
#define GLOAD_LDS16(g,l) __builtin_amdgcn_global_load_lds( \
  (const __attribute__((address_space(1))) void*)(g), \
  (__attribute__((address_space(3))) void*)(l), 16, 0, 0)

__constant__ int ZB10c[11] = {0,1,10,35,84,165,286,455,680,969,1330};
__constant__ int B2OFFc[7] = {0,1,10,35,84,165,286};
__constant__ int HOFFc[7]  = {0,1,6,19,44,85,146};
// E8c[q] = exp(-2*pi*i*q/8)
__constant__ float2 E8c[8] = {
  { 1.f, 0.f}, { 0.70710678118654752f,-0.70710678118654752f},
  { 0.f,-1.f}, {-0.70710678118654752f,-0.70710678118654752f},
  {-1.f, 0.f}, {-0.70710678118654752f, 0.70710678118654752f},
  { 0.f, 1.f}, { 0.70710678118654752f, 0.70710678118654752f}};

// wave-synchronous phase fence
#define WFENCE do{ __builtin_amdgcn_sched_barrier(0); \
  asm volatile("s_waitcnt lgkmcnt(0)" ::: "memory"); \
  __builtin_amdgcn_sched_barrier(0); }while(0)

// half-space H = { (m,n): n>0 } U { (m,n): n==0 && m>=0 }
__device__ inline void h_decode(int h, int& l, int& m, int& n){
  l=0; while(HOFFc[l+1]<=h) ++l;
  int r=h-HOFFc[l], L=2*l+1;
  if(r<l+1){ n=0; m=r; }
  else { int q=r-(l+1); n=q/L+1; m=q%L-l; }
}

// ---------------- double-precision table generation helpers ----------------
__device__ inline double ipow_d(double x, int n){ double r=1.0; for(int i=0;i<n;++i) r*=x; return r; }

// wigd with factorial table (values identical to iterative dfact)
__device__ double wigd_t(int l, int mp, int m, double beta, const double* F){
  double cb=cos(0.5*beta), sb=sin(0.5*beta);
  double pref=sqrt(F[l+mp]*F[l-mp]*F[l+m]*F[l-m]);
  int s0 = (m-mp>0) ? (m-mp) : 0;
  int s1 = (l+m < l-mp) ? (l+m) : (l-mp);
  double acc=0.0;
  for(int s=s0;s<=s1;++s){
    double den=F[l+m-s]*F[s]*F[mp-m+s]*F[l-mp-s];
    double t=ipow_d(cb,2*l+m-mp-2*s)*ipow_d(sb,mp-m+2*s)/den;
    acc += ((mp-m+s)&1)? -t : t;
  }
  return pref*acc;
}

__device__ double dhw(int b, int j){
  double beta=PI_D*(2*j+1)/(4.0*b);
  double s=0.0;
  for(int k=0;k<b;++k) s += sin((2*k+1)*beta)/(2*k+1);
  return (2.0/b)*sin(beta)*s;
}

// ---------------- single merged table-generation kernel (+KA) ----------------
// beta->pi-beta symmetry: d^l_{m',m}(pi-b) = (-1)^{l+m} d^l_{-m',m}(b)
__global__ void gen_all(const float* __restrict__ k2,
                        float* A1, float* D1SJ, float* W3H, float* D2SJ,
                        float* D3_2, float* D3_1, float* WINT,
                        float2* E60, float2* E20, float2* E12,
                        unsigned* zLUT, unsigned* xh2LUT, unsigned* h2LUT,
                        unsigned short* fhLUT, unsigned* aLUT,
                        float2* KA){
  __shared__ double factS[21];
  __shared__ double dhwS[60];
  __shared__ float2 E8L[8];
  int blk=blockIdx.x, t=threadIdx.x;
  if(t==0){ double f=1.0; factS[0]=1.0; for(int k=1;k<=20;++k){ f*=(double)k; factS[k]=f; } }
  if(blk<24){ if(t<60) dhwS[t]=dhw(30,t); }
  else if(blk>=76 && blk<82){ if(t<20) dhwS[t]=dhw(10,t); }
  if(t<8) E8L[t]=E8c[t];
  __syncthreads();
  const double* F=factS;
  if(blk<24){                     // A1: [j][s1], 60x100
    int idx=blk*256+t;
    if(idx<6000){
      int j=idx/NS1, s=idx%NS1;
      int l=0; while((l+1)*(l+1)<=s) ++l;
      int m=s-l*l-l;
      double beta=PI_D*(2*j+1)/120.0;
      A1[idx]=(float)(wigd_t(l,m,0,beta,F)*dhwS[j]*(2.0*PI_D/60.0));
    }
  } else if(blk<76){              // D1SJ: j=0..9 computed, 19-j derived
    int idx=(blk-24)*256+t; if(idx>=13300) return;
    int j=idx/1330, s=idx%1330;
    int l=0; while(ZB10c[l+1]<=s) ++l;
    int r=s-ZB10c[l]; int L=2*l+1;
    int mi=r/L, ni=r%L;
    double beta=PI_D*(2*j+1)/40.0;
    float v=(float)((2*l+1)*wigd_t(l,mi-l,ni-l,beta,F));
    D1SJ[j*1330+s]=v;
    int s2=ZB10c[l]+(2*l-mi)*L+ni;
    D1SJ[(19-j)*1330+s2]=(ni&1)? -v : v;
  } else if(blk<82){              // W3H: j=0..9 computed, 19-j derived
    int idx=(blk-76)*256+t;
    if(idx<10*NH2){
      int j=idx/NH2, h=idx%NH2;
      int l,m,n; h_decode(h,l,m,n);
      double beta=PI_D*(2*j+1)/40.0;
      double c=2.0*PI_D/20.0;
      float v=(float)(wigd_t(l,m,n,beta,F)*dhwS[j]*c*c);
      W3H[j*NH2+h]=v;
      if(n==0){
        W3H[(19-j)*NH2+h]=((l+m)&1)? -v : v;
      } else {
        int L=2*l+1;
        int hp=HOFFc[l]+(l+1)+(n-1)*L+(l-m);   // (m,n) -> (-m,n)
        W3H[(19-j)*NH2+hp]=((l+n)&1)? -v : v;
      }
    }
  } else if(blk<89){              // D2SJ: j=0..5 computed, 11-j derived
    int idx=(blk-82)*256+t; if(idx>=1716) return;
    int j=idx/286, s=idx%286;
    int l=0; while(B2OFFc[l+1]<=s) ++l;
    int r=s-B2OFFc[l]; int L=2*l+1;
    int mi=r/L, ni=r%L;
    double beta=PI_D*(2*j+1)/24.0;
    float v=(float)((2*l+1)*wigd_t(l,mi-l,ni-l,beta,F));
    D2SJ[j*286+s]=v;
    int s2=B2OFFc[l]+(2*l-mi)*L+ni;
    D2SJ[(11-j)*286+s2]=(ni&1)? -v : v;
  } else if(blk<93){              // D3_2: [bi][286]
    int idx=(blk-89)*256+t; if(idx>=3*286) return;
    int bi=idx/286, s=idx%286;
    int l=0; while(B2OFFc[l+1]<=s) ++l;
    int r=s-B2OFFc[l]; int L=2*l+1;
    int mi=r/L, ni=r%L;
    double beta=(bi+1)*(PI_D/8.0)/3.0;
    D3_2[idx]=(float)wigd_t(l,mi-l,ni-l,beta,F);
  } else if(blk<95){              // D3_1: [bi][100]
    int idx=(blk-93)*256+t; if(idx>=3*100) return;
    int bi=idx/100, s=idx%100;
    int l=0; while((l+1)*(l+1)<=s) ++l;
    int m=s-l*l-l;
    double beta=(bi+1)*(PI_D/8.0)/3.0;
    D3_1[idx]=(float)wigd_t(l,m,0,beta,F);
  } else if(blk==95){             // misc
    if(t<12){ double c=2.0*PI_D/12.0; WINT[t]=(float)(dhw(6,t)*c*c); }
    if(t<60){ double a=2.0*PI_D*t/60.0; E60[t]=make_float2((float)cos(a),(float)sin(a)); }
    if(t<20){ double a=2.0*PI_D*t/20.0; E20[t]=make_float2((float)cos(a),(float)sin(a)); }
    if(t<12){ double a=2.0*PI_D*t/12.0; E12[t]=make_float2((float)cos(a),(float)sin(a)); }
  } else if(blk<102){             // zLUT[1330]: packed s1x | s1k<<16
    int idx=(blk-96)*256+t; if(idx>=1330) return;
    int l=0; while(ZB10c[l+1]<=idx) ++l;
    int r=idx-ZB10c[l], L=2*l+1;
    int mi=r/L, ni=r%L;
    unsigned s1x=(unsigned)(l*l+mi), s1k=(unsigned)(l*l+ni);
    zLUT[idx]=s1x|(s1k<<16);
  } else if(blk==102){            // xh2LUT, h2LUT, fhLUT
    if(t<146){
      int l,m,n; h_decode(t,l,m,n);
      int L=2*l+1;
      int s2 =B2OFFc[l]+(m+l)*L+(n+l);
      int s2p=B2OFFc[l]+(l-m)*L+(l-n);
      unsigned sg=(unsigned)((m+n)&1);
      xh2LUT[t]=(unsigned)s2 | ((unsigned)s2p<<10) | (sg<<20);
      h2LUT[t]=(unsigned)l | ((unsigned)(m+l)<<4) | ((unsigned)(n+l)<<8) | ((unsigned)s2<<12);
      fhLUT[t]=(unsigned short)((n==0)? m : 6+(n-1)*11+(m+5));
    }
  } else if(blk==103){            // aLUT[181] sorted by lmin
    if(t==0){
      int idx=0;
      for(int lm=0;lm<10;++lm){
        for(int m=0;m<10;++m){
          int nlo=(m==0)?0:-9;
          for(int n=nlo;n<10;++n){
            int an=n<0?-n:n;
            int lmin=m>an?m:an;
            if(lmin!=lm) continue;
            int L=2*lm+1;
            int zi=ZB10c[lm]+(m+lm)*L+(n+lm);
            aLUT[idx++]=(unsigned)zi | ((unsigned)m<<11) | ((unsigned)(n+9)<<15) | ((unsigned)lm<<20);
          }
        }
      }
    }
  } else {                        // blk 104..703: KA (k2 gamma-DFT)
    int idx=(blk-104)*256+t;
    if(idx<153600){
      int ai=idx&7, q=(idx>>3)&7;
      int r2=idx>>6;
      int bi=r2%3, io=r2/3;
      const float* kp=k2+(size_t)io*192+bi*64+ai*8;
      v2f acc={0.f,0.f};
      int ph=0;
      #pragma unroll
      for(int gi=0;gi<8;++gi){
        acc=PKFMA(bc2(kp[gi]), ldv(&E8L[ph]), acc);
        ph=(ph+q)&7;
      }
      KA[(size_t)io*192+bi*64+q*8+ai]=make_float2(acc.x,acc.y);
    }
  }
}

// ---------------- front: per-b DFT+S2 analysis | k1h ----------------
__global__ __launch_bounds__(256) void front_k(const float* __restrict__ x,
    const float* __restrict__ k1,
    const float2* __restrict__ E60, const float* __restrict__ A1,
    const float* __restrict__ D3_1,
    float2* __restrict__ XHAT, float2* __restrict__ K1H){
  int blk=blockIdx.x, t=threadIdx.x;
  if(blk<128){
    __shared__ __align__(16) float xs[3600];
    __shared__ float2 E60s[60];      // conjugated twiddles
    __shared__ float2 XFs[1140];     // [j][mi], mi = m+9
    if(t<60){ float2 e=E60[t]; E60s[t]=make_float2(e.x,-e.y); }
    {
      const float4* src=(const float4*)(x+blk*3600);
      float4* dst=(float4*)xs;
      for(int i=t;i<900;i+=256) GLOAD_LDS16(src+i, dst+(i&~63));
    }
    __syncthreads();
    // radix-2: x(a)+/-x(a+30) with e^{-im(a+30)} = (-1)^m e^{-ima}
    for(int idx=t; idx<1140; idx+=256){
      int j=idx/19, mi=idx%19;
      int step=(mi<9)? mi+51 : mi-9;
      bool modd = ((mi&1)==0);       // parity(mi-9) = !parity(mi)
      const float* xr=xs+j*60;
      v2f acc={0.f,0.f};
      int k=0;
      for(int a=0;a<30;++a){
        float xv = modd ? (xr[a]-xr[a+30]) : (xr[a]+xr[a+30]);
        acc=PKFMA(bc2(xv), ldv(&E60s[k]), acc);
        k+=step; if(k>=60)k-=60;
      }
      XFs[idx]=make_float2(acc.x,acc.y);
    }
    __syncthreads();
    for(int s=t; s<100; s+=256){
      int l=0; while((l+1)*(l+1)<=s) ++l;
      int m=s-l*l-l;
      const float2* xf=&XFs[m+9];
      v2f acc={0.f,0.f};
      for(int j=0;j<60;++j){
        acc=PKFMA(bc2(A1[j*NS1+s]), ldv(&xf[j*19]), acc);
      }
      XHAT[blk*NS1+s]=make_float2(acc.x,acc.y);
    }
  } else {
    __shared__ float2 E8s[8];
    if(t<8) E8s[t]=E8c[t];
    __syncthreads();
    int idx=(blk-128)*256+t;
    if(idx<F1*NS1){
      int o=idx/NS1, s=idx%NS1;
      int l=0; while((l+1)*(l+1)<=s) ++l;
      int m=s-l*l-l;
      int mm=m&7;
      v2f acc={0.f,0.f};
      for(int bi=0;bi<3;++bi){
        v2f sum={0.f,0.f};
        int q=0;
        #pragma unroll
        for(int ai=0;ai<8;++ai){
          sum=PKFMA(bc2(k1[o*24+bi*8+ai]), ldv(&E8s[q]), sum);
          q=(q+mm)&7;
        }
        acc=PKFMA(bc2(D3_1[bi*100+s]), sum, acc);
      }
      const float SC1f = 0.06123724356957945f;
      K1H[idx]=make_float2(acc.x*SC1f, acc.y*SC1f);
    }
  }
}

// fused1: 8-wave wave-per-j barrier-free pipeline, packed-fp32 + radix-2.
// XH2 layout: [b][s2][i]
__global__ __launch_bounds__(512,6) void fused1(
    const float2* __restrict__ XHAT, const float2* __restrict__ K1H,
    const float* __restrict__ D1SJ, const float* __restrict__ W3H,
    const float2* __restrict__ E20, const float* __restrict__ bias1,
    const unsigned* __restrict__ zLUT, const unsigned* __restrict__ xh2LUT,
    const unsigned short* __restrict__ fhLUT, const unsigned* __restrict__ aLUT,
    float2* __restrict__ XH2){
  const int b=blockIdx.x, o=blockIdx.y, t=threadIdx.x;
  const int ln=t&63, w=t>>6;
  __shared__ __align__(16) float2 zS[1330];
  __shared__ __align__(16) float2 TWE2[400];  // [r][k] = e^{i r k th}, 20x20
  __shared__ __align__(16) float2 regA[8][200];
  __shared__ __align__(16) float2 regB[8][190];

  for(int idx=t; idx<400; idx+=512){
    int r=idx/20, c=idx%20;
    TWE2[idx]=E20[(r*c)%20];
  }
  {
    float2* st=regA[0];   // xh rows staged: [0..99]=XHAT row, [100..199]=K1H row
    if(t<100) st[t]=XHAT[b*NS1+t];
    else if(t<200) st[t]=K1H[o*NS1+(t-100)];
  }
  __syncthreads();
  {
    const float2* st=regA[0];
    for(int idx=t; idx<1330; idx+=512){
      unsigned u=zLUT[idx];
      v2f xa=ldv(&st[u&0xffff]);
      v2f kb=ldv(&st[100+(u>>16)]);
      v2f p1=xa*kb, p2=xa*SW(kb);
      zS[idx]=make_float2(p1.x+p1.y, p2.y-p2.x);   // xa*conj(kb)
    }
  }
  __syncthreads();

  const float bb1=bias1[o];
  float2* G  = regA[w];
  float*  vbF= (float*)regA[w];
  float2* Fq = regA[w];
  float*  RB = (float*)regB[w];   // Sx[0..180) Sy[180..360) T0[360..380)
  float*  Sx = RB;
  float*  Sy = RB+180;
  float*  T0f= RB+360;
  float2* U_T= regB[w];           // reuse after C
  v2f fa0={0.f,0.f}, fa1=fa0, fa2=fa0;

  // B-phase twiddle rows: n=c-9 -> row (c+11)%20
  const int BROW[19]={11,12,13,14,15,16,17,18,19,0,1,2,3,4,5,6,7,8,9};

  for(int jq=0;jq<3;++jq){
    const int j=jq*8+w;
    const bool act=(j<20);
    const float* Dg=D1SJ + (act? j*1330 : 0);
    // A: Wigner-beta contraction, half-space (181 items, lmin-sorted LUT)
    if(act) for(int idx=ln; idx<181; idx+=64){
      unsigned au=aLUT[idx];
      int zi=au&2047;
      int m=(au>>11)&15, n9=(au>>15)&31, l=(au>>20)&15;
      int L=2*l+1;
      int m2=2*m+2;
      v2f a0={0.f,0.f};
      for(; l<10; ++l){
        a0=PKFMA(ldv(&zS[zi]), bc2(Dg[zi]), a0);
        zi += L*L + 2*L + m2; L += 2;
      }
      *(v2f*)&G[m*19+n9]=a0;
    }
    WFENCE;
    // B: radix-2 split S_m(g)/S_m(g+10): 45 items (mb x g-pair) + T0 (5 items)
    if(act){
    if(ln<45){
      int mb=ln/5+1, gp=(ln%5)*2;
      const float2* Gr=&G[mb*19];
      v2f E1a={0.f,0.f},E2a=E1a,O1a=E1a,O2a=E1a;
      v2f E1b=E1a,E2b=E1a,O1b=E1a,O2b=E1a;
      #pragma unroll
      for(int c=0;c<19;++c){
        v2f gv=ldv(&Gr[c]);
        const float* er=(const float*)&TWE2[BROW[c]*20+gp];
        float4 e01=*(const float4*)er;
        v2f e0={e01.x,e01.y}, e1={e01.z,e01.w};
        if(c&1){   // c odd -> n=c-9 even -> E
          E1a=PKFMA(gv,e0,E1a); E2a=PKFMA(gv,SW(e0),E2a);
          E1b=PKFMA(gv,e1,E1b); E2b=PKFMA(gv,SW(e1),E2b);
        } else {   // n odd -> O
          O1a=PKFMA(gv,e0,O1a); O2a=PKFMA(gv,SW(e0),O2a);
          O1b=PKFMA(gv,e1,O1b); O2b=PKFMA(gv,SW(e1),O2b);
        }
      }
      int si=(mb-1)*20+gp;
      float exa=E1a.x-E1a.y, oxa=O1a.x-O1a.y;
      float eya=E2a.x+E2a.y, oya=O2a.x+O2a.y;
      float exb=E1b.x-E1b.y, oxb=O1b.x-O1b.y;
      float eyb=E2b.x+E2b.y, oyb=O2b.x+O2b.y;
      *(v2f*)&Sx[si]   =(v2f){2.f*(exa+oxa), 2.f*(exb+oxb)};
      *(v2f*)&Sx[si+10]=(v2f){2.f*(exa-oxa), 2.f*(exb-oxb)};
      *(v2f*)&Sy[si]   =(v2f){2.f*(eya+oya), 2.f*(eyb+oyb)};
      *(v2f*)&Sy[si+10]=(v2f){2.f*(eya-oya), 2.f*(eyb-oyb)};
    } else if(ln<50){
      int gt=(ln-45)*2;
      float g0x=G[9].x;
      float Ea=0.f,Eb=0.f,Oa=0.f,Ob=0.f;
      #pragma unroll
      for(int n=1;n<10;++n){
        float2 gv=G[9+n];
        const float* er=(const float*)&TWE2[n*20+gt];
        float4 e01=*(const float4*)er;
        float ra=gv.x*e01.x-gv.y*e01.y;
        float rb=gv.x*e01.z-gv.y*e01.w;
        if((n&1)==0){ Ea+=ra; Eb+=rb; } else { Oa+=ra; Ob+=rb; }
      }
      T0f[gt]   =g0x+2.f*(Ea+Oa);
      T0f[gt+1] =g0x+2.f*(Eb+Ob);
      T0f[gt+10]=g0x+2.f*(Ea-Oa);
      T0f[gt+11]=g0x+2.f*(Eb-Ob);
    }
    }
    WFENCE;
    // C: radix-2 split v(a,g)/v(a+10,g): 50 items (a=0..9 x 4-g), bias+relu
    if(act && ln<50){
      int a=ln/5, g0=(ln%5)*4;
      v2f i01={T0f[g0]+bb1, T0f[g0+1]+bb1};
      v2f i23={T0f[g0+2]+bb1, T0f[g0+3]+bb1};
      v2f P01={0.f,0.f},P23=P01,Q01=P01,Q23=P01;
      #pragma unroll
      for(int m=1;m<10;++m){
        float2 e=TWE2[a*20+m];
        v2f sx01=*(const v2f*)&Sx[(m-1)*20+g0];
        v2f sx23=*(const v2f*)&Sx[(m-1)*20+g0+2];
        v2f sy01=*(const v2f*)&Sy[(m-1)*20+g0];
        v2f sy23=*(const v2f*)&Sy[(m-1)*20+g0+2];
        if(m&1){
          Q01=PKFMA(bc2(e.x),sx01,Q01); Q01=PKFMA(bc2(-e.y),sy01,Q01);
          Q23=PKFMA(bc2(e.x),sx23,Q23); Q23=PKFMA(bc2(-e.y),sy23,Q23);
        } else {
          P01=PKFMA(bc2(e.x),sx01,P01); P01=PKFMA(bc2(-e.y),sy01,P01);
          P23=PKFMA(bc2(e.x),sx23,P23); P23=PKFMA(bc2(-e.y),sy23,P23);
        }
      }
      v2f z2={0.f,0.f};
      v2f vA01=i01+P01+Q01, vA23=i23+P23+Q23;
      v2f vB01=i01+P01-Q01, vB23=i23+P23-Q23;
      *(v2f*)&vbF[a*20+g0]       =__builtin_elementwise_max(vA01,z2);
      *(v2f*)&vbF[a*20+g0+2]     =__builtin_elementwise_max(vA23,z2);
      *(v2f*)&vbF[(a+10)*20+g0]  =__builtin_elementwise_max(vB01,z2);
      *(v2f*)&vbF[(a+10)*20+g0+2]=__builtin_elementwise_max(vB23,z2);
    }
    WFENCE;
    // D: radix-2 input split U_T[nu][a]=sum_{g<10}(v(a,g)+/-v(a,g+10))e^{-i nu g}
    if(act && ln<60){
      int a=ln/3, np=ln%3;
      int nu0=2*np, nu1=2*np+1;
      int r0=(np==0)?0:(20-2*np);
      int r1=19-2*np;
      const float* vp=&vbF[a*20];
      const float2* T0r=&TWE2[r0*20];
      const float2* T1r=&TWE2[r1*20];
      v2f u0={0.f,0.f}, u1=u0;
      #pragma unroll
      for(int g=0;g<10;++g){
        float va=vp[g], vb=vp[g+10];
        u0=PKFMA(bc2(va+vb), ldv(&T0r[g]), u0);
        u1=PKFMA(bc2(va-vb), ldv(&T1r[g]), u1);
      }
      *(v2f*)&U_T[nu0*20+a]=u0; *(v2f*)&U_T[nu1*20+a]=u1;
    }
    WFENCE;
    // E: radix-2 input split Fq(mu,nu)=sum_{a<10}(U[a]+/-U[a+10])e^{-i mu a}
    if(act && ln<61){
      int mu,nu;
      if(ln<6){ mu=ln; nu=0; } else { int q=ln-6; nu=q/11+1; mu=q%11-5; }
      int mm=(mu+20)%20;
      int rm=(20-mm)%20;
      bool modd=(mm&1);
      const float2* Ur=&U_T[nu*20];
      const float2* Er=&TWE2[rm*20];
      v2f p1={0.f,0.f}, p2=p1;
      #pragma unroll
      for(int a=0;a<10;++a){
        v2f ua=ldv(&Ur[a]), ub=ldv(&Ur[a+10]);
        v2f u = modd ? (ua-ub) : (ua+ub);
        v2f e=ldv(&Er[a]);
        p1=PKFMA(u,e,p1);
        p2=PKFMA(u,SW(e),p2);
      }
      Fq[ln]=make_float2(p1.x-p1.y, p2.x+p2.y);
    }
    WFENCE;
    // F: accumulate half-s2 with W3H into registers
    if(act){
      const float* W3r=W3H + j*NH2;
      fa0=PKFMA(bc2(W3r[ln]),    ldv(&Fq[fhLUT[ln]]),    fa0);
      fa1=PKFMA(bc2(W3r[64+ln]), ldv(&Fq[fhLUT[64+ln]]), fa1);
      if(ln<18) fa2=PKFMA(bc2(W3r[128+ln]), ldv(&Fq[fhLUT[128+ln]]), fa2);
    }
    WFENCE;
  }
  // spill register accumulators, merge 8 waves, expand half->full by conjugation
  regB[w][ln]=make_float2(fa0.x,fa0.y);
  regB[w][64+ln]=make_float2(fa1.x,fa1.y);
  if(ln<18) regB[w][128+ln]=make_float2(fa2.x,fa2.y);
  __syncthreads();
  for(int h=t; h<146; h+=512){
    unsigned u=xh2LUT[h];
    int s2=u&1023, s2p=(u>>10)&1023;
    float sg=((u>>20)&1)? -1.f : 1.f;
    float2 a0=regB[0][h], a1=regB[1][h], a2=regB[2][h], a3=regB[3][h];
    float2 a4=regB[4][h], a5=regB[5][h], a6=regB[6][h], a7=regB[7][h];
    float2 a=make_float2(a0.x+a1.x+a2.x+a3.x+a4.x+a5.x+a6.x+a7.x,
                         a0.y+a1.y+a2.y+a3.y+a4.y+a5.y+a6.y+a7.y);
    XH2[(b*286+s2 )*F1+o]=a;
    XH2[(b*286+s2p)*F1+o]=make_float2(sg*a.x, -sg*a.y);
  }
}

// K2H: block per (i,o); KA row staged to LDS once; 146 h-threads consume.
// K2H layout: [o][s2][i]
__global__ __launch_bounds__(192) void k2h_k(const float2* __restrict__ KA,
                      const float* __restrict__ D3_2,
                      const unsigned* __restrict__ h2LUT, const unsigned* __restrict__ xh2LUT,
                      float2* __restrict__ K2H){
  __shared__ float2 kaS[192];
  __shared__ float2 E8s[8];
  int io=blockIdx.x, t=threadIdx.x;
  int i=io/F2, o=io%F2;
  if(t<8) E8s[t]=E8c[t];
  kaS[t]=KA[(size_t)io*192+t];
  __syncthreads();
  if(t>=146) return;
  unsigned hu=h2LUT[t];
  int l=hu&15, mi=(hu>>4)&15, ni=(hu>>8)&15, s2=hu>>12;
  int m=mi-l, n=ni-l;
  unsigned xu=xh2LUT[t];
  int s2p=(xu>>10)&1023;
  float sg=((xu>>20)&1)? -1.f : 1.f;
  int q=n&7, p=(m-n)&7;
  v2f a1={0.f,0.f}, a2=a1;
  for(int bi=0;bi<3;++bi){
    const float2* kp=&kaS[bi*64+q*8];
    v2f s1={0.f,0.f}, s2v=s1;
    int ph=0;
    #pragma unroll
    for(int ai=0;ai<8;++ai){
      v2f ka=ldv(&kp[ai]), e=ldv(&E8s[ph]);
      s1=PKFMA(ka,e,s1); s2v=PKFMA(ka,SW(e),s2v);
      ph=(ph+p)&7;
    }
    v2f dv=bc2(D3_2[bi*286+s2]);
    a1=PKFMA(dv,s1,a1); a2=PKFMA(dv,s2v,a2);
  }
  const float SC2f = 0.034722222222222224f;
  float re=(a1.x-a1.y)*SC2f, im=(a2.x+a2.y)*SC2f;
  K2H[((size_t)o*286+s2)*F1+i]=make_float2(re,im);
  K2H[((size_t)o*286+s2p)*F1+i]=make_float2(sg*re,-sg*im);
}

// fused2: cooperative z2 build (3 l-groups, 4-way i-split), then wave-per-3j
// single-pass synthesis+integrate (round-13 structure)
__global__ __launch_bounds__(256,3) void fused2(
    const float2* __restrict__ XH2, const float2* __restrict__ K2H,
    const float* __restrict__ D2SJ, const float* __restrict__ WINT,
    const float2* __restrict__ E12, const float* __restrict__ bias2,
    const unsigned* __restrict__ h2LUT, const unsigned* __restrict__ xh2LUT,
    float* __restrict__ FEAT){
  const int b=blockIdx.x, o=blockIdx.y, t=threadIdx.x;
  const int ln=t&63, w=t>>6;
  __shared__ __align__(16) float2 Xs[2420];
  __shared__ __align__(16) float2 Ks[2420];
  __shared__ float2 zpS[1144];
  __shared__ float2 z2S[286];
  __shared__ float  redS[256];
  float2* alias=(float2*)Xs;       // reused after z-build
  float2* TWE12=alias;             // [12][12]: e^{i r c th12}

  const int gb[4]={0,84,165,286};
  const int hb[4]={0,44,85,146};
  for(int grp=0; grp<3; ++grp){
    int row0=gb[grp], rows=gb[grp+1]-row0;
    {
      int cnt4=rows*10;
      const float4* xsrc=(const float4*)(XH2+(size_t)(b*286+row0)*F1);
      const float4* ksrc=(const float4*)(K2H+(size_t)(o*286+row0)*F1);
      float4* xd=(float4*)Xs; float4* kd=(float4*)Ks;
      for(int i4=t;i4<cnt4;i4+=256){
        int wb=i4&~63;
        GLOAD_LDS16(xsrc+i4, xd+wb);
        GLOAD_LDS16(ksrc+i4, kd+wb);
      }
    }
    __syncthreads();
    int nh=hb[grp+1]-hb[grp];
    for(int idx=t; idx<4*nh; idx+=256){
      int hl=idx>>2, iq=idx&3;
      int h=hb[grp]+hl;
      unsigned hu=h2LUT[h];
      int l=hu&15, mi=(hu>>4)&15, ni=(hu>>8)&15, s2=hu>>12;
      int L=2*l+1;
      int xr0=(B2OFFc[l]-row0)+mi*L;
      int kr0=(B2OFFc[l]-row0)+ni*L;
      v2f p1={0.f,0.f}, p2=p1;
      for(int k=0;k<L;++k){
        const float2* xp=Xs+(xr0+k)*F1+iq*5;
        const float2* kp=Ks+(kr0+k)*F1+iq*5;
        #pragma unroll
        for(int i=0;i<5;++i){
          v2f xa=ldv(&xp[i]), kb=ldv(&kp[i]);
          p1=PKFMA(xa,kb,p1);
          p2=PKFMA(xa,SW(kb),p2);
        }
      }
      zpS[iq*286+s2]=make_float2(p1.x+p1.y, p2.y-p2.x);
    }
    __syncthreads();
  }
  for(int idx=t; idx<146; idx+=256){
    unsigned xu=xh2LUT[idx];
    int s2=xu&1023, s2p=(xu>>10)&1023;
    float sg=((xu>>20)&1)? -1.f : 1.f;
    float2 a;
    a.x=zpS[0*286+s2].x+zpS[1*286+s2].x+zpS[2*286+s2].x+zpS[3*286+s2].x;
    a.y=zpS[0*286+s2].y+zpS[1*286+s2].y+zpS[2*286+s2].y+zpS[3*286+s2].y;
    z2S[s2]=a;
    z2S[s2p]=make_float2(sg*a.x,-sg*a.y);
  }
  __syncthreads();
  for(int idx=t; idx<144; idx+=256){
    int r=idx/12, c=idx%12;
    TWE12[idx]=E12[(r*c)%12];
  }
  __syncthreads();

  float2* base2=alias+144+w*400;
  float2* G2_0=base2; float2* G2_1=base2+66; float2* G2_2=base2+132;
  float*  SP=(float*)(base2+198);
  float*  S2x0=SP, *S2x1=SP+60, *S2x2=SP+120;
  float*  S2y0=SP+180, *S2y1=SP+240, *S2y2=SP+300;
  float*  T02=SP+360;               // [3][12]
  float personal=0.f;
  const float b2v=bias2[o];
  const int j0=3*w, j1=3*w+1, j2=3*w+2;
  const float* Dg0=D2SJ + j0*286;
  const float* Dg1=D2SJ + j1*286;
  const float* Dg2=D2SJ + j2*286;
  const int BR12[11]={7,8,9,10,11,0,1,2,3,4,5};

  // A2: 61 half items, 3 j's
  if(ln<61){
    int m,n;
    if(ln<6){m=0;n=ln;} else {int qq=ln-6;m=qq/11+1;n=qq%11-5;}
    int an=n<0?-n:n; int l=m>an?m:an; int L=2*l+1;
    int zi=B2OFFc[l]+(m+l)*L+(n+l); int m2=2*m+2;
    v2f a0={0.f,0.f}, a1=a0, a2=a0;
    for(;l<6;++l){
      v2f zv=ldv(&z2S[zi]);
      a0=PKFMA(zv, bc2(Dg0[zi]), a0);
      a1=PKFMA(zv, bc2(Dg1[zi]), a1);
      a2=PKFMA(zv, bc2(Dg2[zi]), a2);
      zi+=L*L+2*L+m2; L+=2;
    }
    int gi=m*11+(n+5);
    *(v2f*)&G2_0[gi]=a0; *(v2f*)&G2_1[gi]=a1; *(v2f*)&G2_2[gi]=a2;
  }
  WFENCE;
  // B2: radix-2 (g,g+6) split over n-parity: 30 items + 12 T0, 3 j's
  if(ln<30){
    int m=ln/6+1, g=ln%6;
    v2f E1_0={0.f,0.f},E2_0=E1_0,O1_0=E1_0,O2_0=E1_0;
    v2f E1_1=E1_0,E2_1=E1_0,O1_1=E1_0,O2_1=E1_0;
    v2f E1_2=E1_0,E2_2=E1_0,O1_2=E1_0,O2_2=E1_0;
    #pragma unroll
    for(int c=0;c<11;++c){
      float2 ef=TWE12[BR12[c]*12+g];
      v2f e={ef.x,ef.y};
      v2f g0=ldv(&G2_0[m*11+c]), g1=ldv(&G2_1[m*11+c]), g2=ldv(&G2_2[m*11+c]);
      if(c&1){  // n=c-5 even -> E
        E1_0=PKFMA(g0,e,E1_0); E2_0=PKFMA(g0,SW(e),E2_0);
        E1_1=PKFMA(g1,e,E1_1); E2_1=PKFMA(g1,SW(e),E2_1);
        E1_2=PKFMA(g2,e,E1_2); E2_2=PKFMA(g2,SW(e),E2_2);
      } else {  // n odd -> O
        O1_0=PKFMA(g0,e,O1_0); O2_0=PKFMA(g0,SW(e),O2_0);
        O1_1=PKFMA(g1,e,O1_1); O2_1=PKFMA(g1,SW(e),O2_1);
        O1_2=PKFMA(g2,e,O1_2); O2_2=PKFMA(g2,SW(e),O2_2);
      }
    }
    int si=(m-1)*12+g;
    {
      float Ex=E1_0.x-E1_0.y, Ox=O1_0.x-O1_0.y;
      float Ey=E2_0.x+E2_0.y, Oy=O2_0.x+O2_0.y;
      S2x0[si]=2.f*(Ex+Ox); S2x0[si+6]=2.f*(Ex-Ox);
      S2y0[si]=2.f*(Ey+Oy); S2y0[si+6]=2.f*(Ey-Oy);
    }
    {
      float Ex=E1_1.x-E1_1.y, Ox=O1_1.x-O1_1.y;
      float Ey=E2_1.x+E2_1.y, Oy=O2_1.x+O2_1.y;
      S2x1[si]=2.f*(Ex+Ox); S2x1[si+6]=2.f*(Ex-Ox);
      S2y1[si]=2.f*(Ey+Oy); S2y1[si+6]=2.f*(Ey-Oy);
    }
    {
      float Ex=E1_2.x-E1_2.y, Ox=O1_2.x-O1_2.y;
      float Ey=E2_2.x+E2_2.y, Oy=O2_2.x+O2_2.y;
      S2x2[si]=2.f*(Ex+Ox); S2x2[si+6]=2.f*(Ex-Ox);
      S2y2[si]=2.f*(Ey+Oy); S2y2[si+6]=2.f*(Ey-Oy);
    }
  } else if(ln<42){
    int g=ln-30;
    float r0=G2_0[5].x, r1=G2_1[5].x, r2=G2_2[5].x;
    #pragma unroll
    for(int n=1;n<6;++n){
      float2 e=TWE12[n*12+g];
      float2 g0=G2_0[5+n], g1=G2_1[5+n], g2=G2_2[5+n];
      r0+=2.f*(g0.x*e.x-g0.y*e.y);
      r1+=2.f*(g1.x*e.x-g1.y*e.y);
      r2+=2.f*(g2.x*e.x-g2.y*e.y);
    }
    T02[g]=r0; T02[12+g]=r1; T02[24+g]=r2;
  }
  WFENCE;
  // C2: 36 items, packed g-pairs, fused relu+integrate, 3 j's
  if(ln<36){
    float w0=WINT[j0], w1=WINT[j1], w2=WINT[j2];
    int a=ln/3, g4=(ln%3)*4;
    v2f iA0={T02[g4]+b2v, T02[g4+1]+b2v},       iB0={T02[g4+2]+b2v, T02[g4+3]+b2v};
    v2f iA1={T02[12+g4]+b2v, T02[12+g4+1]+b2v}, iB1={T02[12+g4+2]+b2v, T02[12+g4+3]+b2v};
    v2f iA2={T02[24+g4]+b2v, T02[24+g4+1]+b2v}, iB2={T02[24+g4+2]+b2v, T02[24+g4+3]+b2v};
    #pragma unroll
    for(int m=1;m<6;++m){
      float2 e=TWE12[a*12+m];
      v2f ex=bc2(e.x), eny=bc2(-e.y);
      int si=(m-1)*12+g4;
      v2f sx, sy;
      sx=*(const v2f*)&S2x0[si];   sy=*(const v2f*)&S2y0[si];
      iA0=PKFMA(ex,sx,iA0); iA0=PKFMA(eny,sy,iA0);
      sx=*(const v2f*)&S2x0[si+2]; sy=*(const v2f*)&S2y0[si+2];
      iB0=PKFMA(ex,sx,iB0); iB0=PKFMA(eny,sy,iB0);
      sx=*(const v2f*)&S2x1[si];   sy=*(const v2f*)&S2y1[si];
      iA1=PKFMA(ex,sx,iA1); iA1=PKFMA(eny,sy,iA1);
      sx=*(const v2f*)&S2x1[si+2]; sy=*(const v2f*)&S2y1[si+2];
      iB1=PKFMA(ex,sx,iB1); iB1=PKFMA(eny,sy,iB1);
      sx=*(const v2f*)&S2x2[si];   sy=*(const v2f*)&S2y2[si];
      iA2=PKFMA(ex,sx,iA2); iA2=PKFMA(eny,sy,iA2);
      sx=*(const v2f*)&S2x2[si+2]; sy=*(const v2f*)&S2y2[si+2];
      iB2=PKFMA(ex,sx,iB2); iB2=PKFMA(eny,sy,iB2);
    }
    v2f z2={0.f,0.f};
    v2f rA0=__builtin_elementwise_max(iA0,z2), rB0=__builtin_elementwise_max(iB0,z2);
    v2f rA1=__builtin_elementwise_max(iA1,z2), rB1=__builtin_elementwise_max(iB1,z2);
    v2f rA2=__builtin_elementwise_max(iA2,z2), rB2=__builtin_elementwise_max(iB2,z2);
    personal += w0*(rA0.x+rA0.y+rB0.x+rB0.y)
              + w1*(rA1.x+rA1.y+rB1.x+rB1.y)
              + w2*(rA2.x+rA2.y+rB2.x+rB2.y);
  }
  redS[t]=personal;
  __syncthreads();
  for(int s=128;s>0;s>>=1){
    if(t<s) redS[t]+=redS[t+s];
    __syncthreads();
  }
  if(t==0) FEAT[b*F2+o]=redS[0];
}

__global__ void head_k(const float* __restrict__ FEAT, const float* __restrict__ w_out,
                       const float* __restrict__ b_lin, float* __restrict__ out){
  int idx=blockIdx.x*blockDim.x+threadIdx.x;
  if(idx>=BATCH*FOUT) return;
  int b=idx/FOUT, q=idx%FOUT;
  float acc=b_lin[q];
  for(int f=0;f<F2;++f) acc += FEAT[b*F2+f]*w_out[q*F2+f];
  out[idx]=acc;
}

extern "C" void kernel_launch(void* const* d_in, const int* in_sizes, int n_in,
                              void* d_out, int out_size, void* d_ws, size_t ws_size,
                              hipStream_t stream) {
  const float* x    =(const float*)d_in[0];
  const float* k1   =(const float*)d_in[1];
  const float* bias1=(const float*)d_in[2];
  const float* k2   =(const float*)d_in[3];
  const float* bias2=(const float*)d_in[4];
  const float* w_out=(const float*)d_in[5];
  const float* b_lin=(const float*)d_in[6];
  float* out=(float*)d_out;

  char* ws=(char*)d_ws;
  float*  A1   =(float* )(ws+0);        //  6000 f
  float*  D1SJ =(float* )(ws+24000);    //  26600 f
  float*  W3H  =(float* )(ws+130400);   //  2920 f
  float*  D2SJ =(float* )(ws+142080);   //  3432 f
  float*  D3_2 =(float* )(ws+155808);   //  858 f (+pad)
  float*  D3_1 =(float* )(ws+159248);   //  300 f
  float*  WINT =(float* )(ws+160448);   //  12 f
  float2* E60  =(float2*)(ws+160496);   //  60 c
  float2* E20  =(float2*)(ws+160976);   //  20 c
  float2* E12  =(float2*)(ws+161136);   //  12 c (+pad)
  unsigned* zLUT=(unsigned*)(ws+161248);//  1330 u32 (+pad)
  unsigned* xh2LUT=(unsigned*)(ws+166576); // 146 u32
  unsigned* h2LUT =(unsigned*)(ws+167160); // 146 u32
  unsigned short* fhLUT=(unsigned short*)(ws+167744); // 146 u16 (+pad)
  unsigned* aLUT =(unsigned*)(ws+168048);  // 181 u32 (+pad)
  float2* XHAT =(float2*)(ws+168784);   //  [b][100] c
  float2* K1H  =(float2*)(ws+271184);   //  [o][100] c
  float2* KA   =(float2*)(ws+287184);   //  153600 c (1.2MB)
  float2* XH2  =(float2*)(ws+1515984);  //  [b][286][20] c
  float2* K2H  =(float2*)(ws+7373264);  //  [o][286][20] c
  float*  FEAT =(float* )(ws+9203664);  //  128*40 f -> 9224144 total

  (void)in_sizes; (void)n_in; (void)out_size; (void)ws_size;

  gen_all<<<704,256,0,stream>>>(k2,A1,D1SJ,W3H,D2SJ,D3_2,D3_1,WINT,E60,E20,E12,
                                zLUT,xh2LUT,h2LUT,fhLUT,aLUT,KA);
  front_k<<<136,256,0,stream>>>(x,k1,E60,A1,D3_1,XHAT,K1H);
  dim3 g1(BATCH,F1);
  fused1<<<g1,512,0,stream>>>(XHAT,K1H,D1SJ,W3H,E20,bias1,zLUT,xh2LUT,fhLUT,aLUT,XH2);
  k2h_k<<<F1*F2,192,0,stream>>>(KA,D3_2,h2LUT,xh2LUT,K2H);
  dim3 g2(BATCH,F2);
  fused2<<<g2,256,0,stream>>>(XH2,K2H,D2SJ,WINT,E12,bias2,h2LUT,xh2LUT,FEAT);
  head_k<<<(BATCH*FOUT+255)/256,256,0,stream>>>(FEAT,w_out,b_lin,out);
}

// Round 17
// 198.178 us; speedup vs baseline: 1.2183x; 1.0229x over previous
//
#include <hip/hip_runtime.h>
#include <math.h>

#define PI_D 3.14159265358979323846

#define BATCH 128
#define F1 20
#define F2 40
#define FOUT 10
#define NS1 100   // sum_{l<10} (2l+1)
#define NS2 286   // sum_{l<6} (2l+1)^2
#define NH2 146   // Hermitian half count of NS2

typedef float v2f __attribute__((ext_vector_type(2)));
#define PKFMA(a,b,c) __builtin_elementwise_fma((a),(b),(c))
#define SW(v) __builtin_shufflevector((v),(v),1,0)
static __device__ __forceinline__ v2f bc2(float s){ return (v2f){s,s}; }
static __device__ __forceinline__ v2f ldv(const float2* p){ return *(const v2f*)p; }

// async global->LDS, 16B per lane; lds arg must be wave-uniform base
#define GLOAD_LDS16(g,l) __builtin_amdgcn_global_load_lds( \
  (const __attribute__((address_space(1))) void*)(g), \
  (__attribute__((address_space(3))) void*)(l), 16, 0, 0)

__constant__ int ZB10c[11] = {0,1,10,35,84,165,286,455,680,969,1330};
__constant__ int B2OFFc[7] = {0,1,10,35,84,165,286};
__constant__ int HOFFc[7]  = {0,1,6,19,44,85,146};
// E8c[q] = exp(-2*pi*i*q/8)
__constant__ float2 E8c[8] = {
  { 1.f, 0.f}, { 0.70710678118654752f,-0.70710678118654752f},
  { 0.f,-1.f}, {-0.70710678118654752f,-0.70710678118654752f},
  {-1.f, 0.f}, {-0.70710678118654752f, 0.70710678118654752f},
  { 0.f, 1.f}, { 0.70710678118654752f, 0.70710678118654752f}};

// wave-synchronous phase fence
#define WFENCE do{ __builtin_amdgcn_sched_barrier(0); \
  asm volatile("s_waitcnt lgkmcnt(0)" ::: "memory"); \
  __builtin_amdgcn_sched_barrier(0); }while(0)

// half-space H = { (m,n): n>0 } U { (m,n): n==0 && m>=0 }
__device__ inline void h_decode(int h, int& l, int& m, int& n){
  l=0; while(HOFFc[l+1]<=h) ++l;
  int r=h-HOFFc[l], L=2*l+1;
  if(r<l+1){ n=0; m=r; }
  else { int q=r-(l+1); n=q/L+1; m=q%L-l; }
}

// ---------------- double-precision table generation helpers ----------------
__device__ inline double ipow_d(double x, int n){ double r=1.0; for(int i=0;i<n;++i) r*=x; return r; }

// wigd with factorial table (values identical to iterative dfact)
__device__ double wigd_t(int l, int mp, int m, double beta, const double* F){
  double cb=cos(0.5*beta), sb=sin(0.5*beta);
  double pref=sqrt(F[l+mp]*F[l-mp]*F[l+m]*F[l-m]);
  int s0 = (m-mp>0) ? (m-mp) : 0;
  int s1 = (l+m < l-mp) ? (l+m) : (l-mp);
  double acc=0.0;
  for(int s=s0;s<=s1;++s){
    double den=F[l+m-s]*F[s]*F[mp-m+s]*F[l-mp-s];
    double t=ipow_d(cb,2*l+m-mp-2*s)*ipow_d(sb,mp-m+2*s)/den;
    acc += ((mp-m+s)&1)? -t : t;
  }
  return pref*acc;
}

__device__ double dhw(int b, int j){
  double beta=PI_D*(2*j+1)/(4.0*b);
  double s=0.0;
  for(int k=0;k<b;++k) s += sin((2*k+1)*beta)/(2*k+1);
  return (2.0/b)*sin(beta)*s;
}

// ---------------- single merged table-generation kernel (+KA) ----------------
// beta->pi-beta symmetry: d^l_{m',m}(pi-b) = (-1)^{l+m} d^l_{-m',m}(b)
__global__ void gen_all(const float* __restrict__ k2,
                        float* A1, float* D1SJ, float* W3H, float* D2SJ,
                        float* D3_2, float* D3_1, float* WINT,
                        float2* E60, float2* E20, float2* E12,
                        unsigned* zLUT, unsigned* xh2LUT, unsigned* h2LUT,
                        unsigned short* fhLUT, unsigned* aLUT,
                        float2* KA){
  __shared__ double factS[21];
  __shared__ double dhwS[60];
  __shared__ float2 E8L[8];
  int blk=blockIdx.x, t=threadIdx.x;
  if(t==0){ double f=1.0; factS[0]=1.0; for(int k=1;k<=20;++k){ f*=(double)k; factS[k]=f; } }
  if(blk<24){ if(t<60) dhwS[t]=dhw(30,t); }
  else if(blk>=76 && blk<82){ if(t<20) dhwS[t]=dhw(10,t); }
  if(t<8) E8L[t]=E8c[t];
  __syncthreads();
  const double* F=factS;
  if(blk<24){                     // A1: [j][s1], 60x100
    int idx=blk*256+t;
    if(idx<6000){
      int j=idx/NS1, s=idx%NS1;
      int l=0; while((l+1)*(l+1)<=s) ++l;
      int m=s-l*l-l;
      double beta=PI_D*(2*j+1)/120.0;
      A1[idx]=(float)(wigd_t(l,m,0,beta,F)*dhwS[j]*(2.0*PI_D/60.0));
    }
  } else if(blk<76){              // D1SJ: j=0..9 computed, 19-j derived
    int idx=(blk-24)*256+t; if(idx>=13300) return;
    int j=idx/1330, s=idx%1330;
    int l=0; while(ZB10c[l+1]<=s) ++l;
    int r=s-ZB10c[l]; int L=2*l+1;
    int mi=r/L, ni=r%L;
    double beta=PI_D*(2*j+1)/40.0;
    float v=(float)((2*l+1)*wigd_t(l,mi-l,ni-l,beta,F));
    D1SJ[j*1330+s]=v;
    int s2=ZB10c[l]+(2*l-mi)*L+ni;
    D1SJ[(19-j)*1330+s2]=(ni&1)? -v : v;
  } else if(blk<82){              // W3H: j=0..9 computed, 19-j derived
    int idx=(blk-76)*256+t;
    if(idx<10*NH2){
      int j=idx/NH2, h=idx%NH2;
      int l,m,n; h_decode(h,l,m,n);
      double beta=PI_D*(2*j+1)/40.0;
      double c=2.0*PI_D/20.0;
      float v=(float)(wigd_t(l,m,n,beta,F)*dhwS[j]*c*c);
      W3H[j*NH2+h]=v;
      if(n==0){
        W3H[(19-j)*NH2+h]=((l+m)&1)? -v : v;
      } else {
        int L=2*l+1;
        int hp=HOFFc[l]+(l+1)+(n-1)*L+(l-m);   // (m,n) -> (-m,n)
        W3H[(19-j)*NH2+hp]=((l+n)&1)? -v : v;
      }
    }
  } else if(blk<89){              // D2SJ: j=0..5 computed, 11-j derived
    int idx=(blk-82)*256+t; if(idx>=1716) return;
    int j=idx/286, s=idx%286;
    int l=0; while(B2OFFc[l+1]<=s) ++l;
    int r=s-B2OFFc[l]; int L=2*l+1;
    int mi=r/L, ni=r%L;
    double beta=PI_D*(2*j+1)/24.0;
    float v=(float)((2*l+1)*wigd_t(l,mi-l,ni-l,beta,F));
    D2SJ[j*286+s]=v;
    int s2=B2OFFc[l]+(2*l-mi)*L+ni;
    D2SJ[(11-j)*286+s2]=(ni&1)? -v : v;
  } else if(blk<93){              // D3_2: [bi][286]
    int idx=(blk-89)*256+t; if(idx>=3*286) return;
    int bi=idx/286, s=idx%286;
    int l=0; while(B2OFFc[l+1]<=s) ++l;
    int r=s-B2OFFc[l]; int L=2*l+1;
    int mi=r/L, ni=r%L;
    double beta=(bi+1)*(PI_D/8.0)/3.0;
    D3_2[idx]=(float)wigd_t(l,mi-l,ni-l,beta,F);
  } else if(blk<95){              // D3_1: [bi][100]
    int idx=(blk-93)*256+t; if(idx>=3*100) return;
    int bi=idx/100, s=idx%100;
    int l=0; while((l+1)*(l+1)<=s) ++l;
    int m=s-l*l-l;
    double beta=(bi+1)*(PI_D/8.0)/3.0;
    D3_1[idx]=(float)wigd_t(l,m,0,beta,F);
  } else if(blk==95){             // misc
    if(t<12){ double c=2.0*PI_D/12.0; WINT[t]=(float)(dhw(6,t)*c*c); }
    if(t<60){ double a=2.0*PI_D*t/60.0; E60[t]=make_float2((float)cos(a),(float)sin(a)); }
    if(t<20){ double a=2.0*PI_D*t/20.0; E20[t]=make_float2((float)cos(a),(float)sin(a)); }
    if(t<12){ double a=2.0*PI_D*t/12.0; E12[t]=make_float2((float)cos(a),(float)sin(a)); }
  } else if(blk<102){             // zLUT[1330]: packed s1x | s1k<<16
    int idx=(blk-96)*256+t; if(idx>=1330) return;
    int l=0; while(ZB10c[l+1]<=idx) ++l;
    int r=idx-ZB10c[l], L=2*l+1;
    int mi=r/L, ni=r%L;
    unsigned s1x=(unsigned)(l*l+mi), s1k=(unsigned)(l*l+ni);
    zLUT[idx]=s1x|(s1k<<16);
  } else if(blk==102){            // xh2LUT, h2LUT, fhLUT
    if(t<146){
      int l,m,n; h_decode(t,l,m,n);
      int L=2*l+1;
      int s2 =B2OFFc[l]+(m+l)*L+(n+l);
      int s2p=B2OFFc[l]+(l-m)*L+(l-n);
      unsigned sg=(unsigned)((m+n)&1);
      xh2LUT[t]=(unsigned)s2 | ((unsigned)s2p<<10) | (sg<<20);
      h2LUT[t]=(unsigned)l | ((unsigned)(m+l)<<4) | ((unsigned)(n+l)<<8) | ((unsigned)s2<<12);
      fhLUT[t]=(unsigned short)((n==0)? m : 6+(n-1)*11+(m+5));
    }
  } else if(blk==103){            // aLUT[181] sorted by lmin
    if(t==0){
      int idx=0;
      for(int lm=0;lm<10;++lm){
        for(int m=0;m<10;++m){
          int nlo=(m==0)?0:-9;
          for(int n=nlo;n<10;++n){
            int an=n<0?-n:n;
            int lmin=m>an?m:an;
            if(lmin!=lm) continue;
            int L=2*lm+1;
            int zi=ZB10c[lm]+(m+lm)*L+(n+lm);
            aLUT[idx++]=(unsigned)zi | ((unsigned)m<<11) | ((unsigned)(n+9)<<15) | ((unsigned)lm<<20);
          }
        }
      }
    }
  } else {                        // blk 104..703: KA (k2 gamma-DFT)
    int idx=(blk-104)*256+t;
    if(idx<153600){
      int ai=idx&7, q=(idx>>3)&7;
      int r2=idx>>6;
      int bi=r2%3, io=r2/3;
      const float* kp=k2+(size_t)io*192+bi*64+ai*8;
      v2f acc={0.f,0.f};
      int ph=0;
      #pragma unroll
      for(int gi=0;gi<8;++gi){
        acc=PKFMA(bc2(kp[gi]), ldv(&E8L[ph]), acc);
        ph=(ph+q)&7;
      }
      KA[(size_t)io*192+bi*64+q*8+ai]=make_float2(acc.x,acc.y);
    }
  }
}

// ---------------- front: per-b DFT+S2 analysis | k1h | k2h ----------------
__global__ __launch_bounds__(256) void front_k(const float* __restrict__ x,
    const float* __restrict__ k1, const float2* __restrict__ KA,
    const float* __restrict__ D3_2,
    const float2* __restrict__ E60, const float* __restrict__ A1,
    const float* __restrict__ D3_1,
    const unsigned* __restrict__ h2LUT, const unsigned* __restrict__ xh2LUT,
    float2* __restrict__ XHAT, float2* __restrict__ K1H, float2* __restrict__ K2H){
  int blk=blockIdx.x, t=threadIdx.x;
  if(blk<128){
    __shared__ __align__(16) float xs[3600];
    __shared__ float2 E60s[60];      // conjugated twiddles
    __shared__ float2 XFs[1140];     // [j][mi], mi = m+9
    if(t<60){ float2 e=E60[t]; E60s[t]=make_float2(e.x,-e.y); }
    {
      const float4* src=(const float4*)(x+blk*3600);
      float4* dst=(float4*)xs;
      for(int i=t;i<900;i+=256) GLOAD_LDS16(src+i, dst+(i&~63));
    }
    __syncthreads();
    // radix-2: x(a)+/-x(a+30) with e^{-im(a+30)} = (-1)^m e^{-ima}
    for(int idx=t; idx<1140; idx+=256){
      int j=idx/19, mi=idx%19;
      int step=(mi<9)? mi+51 : mi-9;
      bool modd = ((mi&1)==0);       // parity(mi-9) = !parity(mi)
      const float* xr=xs+j*60;
      v2f acc={0.f,0.f};
      int k=0;
      for(int a=0;a<30;++a){
        float xv = modd ? (xr[a]-xr[a+30]) : (xr[a]+xr[a+30]);
        acc=PKFMA(bc2(xv), ldv(&E60s[k]), acc);
        k+=step; if(k>=60)k-=60;
      }
      XFs[idx]=make_float2(acc.x,acc.y);
    }
    __syncthreads();
    for(int s=t; s<100; s+=256){
      int l=0; while((l+1)*(l+1)<=s) ++l;
      int m=s-l*l-l;
      const float2* xf=&XFs[m+9];
      v2f acc={0.f,0.f};
      for(int j=0;j<60;++j){
        acc=PKFMA(bc2(A1[j*NS1+s]), ldv(&xf[j*19]), acc);
      }
      XHAT[blk*NS1+s]=make_float2(acc.x,acc.y);
    }
  } else if(blk<136){
    __shared__ float2 E8s[8];
    if(t<8) E8s[t]=E8c[t];
    __syncthreads();
    int idx=(blk-128)*256+t;
    if(idx<F1*NS1){
      int o=idx/NS1, s=idx%NS1;
      int l=0; while((l+1)*(l+1)<=s) ++l;
      int m=s-l*l-l;
      int mm=m&7;
      v2f acc={0.f,0.f};
      for(int bi=0;bi<3;++bi){
        v2f sum={0.f,0.f};
        int q=0;
        #pragma unroll
        for(int ai=0;ai<8;++ai){
          sum=PKFMA(bc2(k1[o*24+bi*8+ai]), ldv(&E8s[q]), sum);
          q=(q+mm)&7;
        }
        acc=PKFMA(bc2(D3_1[bi*100+s]), sum, acc);
      }
      const float SC1f = 0.06123724356957945f;
      K1H[idx]=make_float2(acc.x*SC1f, acc.y*SC1f);
    }
  } else {
    // k2h segment: block per (i,o); KA row staged to LDS once; 146 h-threads.
    // K2H layout: [o][s2][i]
    __shared__ float2 kaS[192];
    __shared__ float2 E8k[8];
    int io=blk-136;
    int i=io/F2, o=io%F2;
    if(t<8) E8k[t]=E8c[t];
    if(t<192) kaS[t]=KA[(size_t)io*192+t];
    __syncthreads();
    if(t>=146) return;
    unsigned hu=h2LUT[t];
    int l=hu&15, mi=(hu>>4)&15, ni=(hu>>8)&15, s2=hu>>12;
    int m=mi-l, n=ni-l;
    unsigned xu=xh2LUT[t];
    int s2p=(xu>>10)&1023;
    float sg=((xu>>20)&1)? -1.f : 1.f;
    int q=n&7, p=(m-n)&7;
    v2f a1={0.f,0.f}, a2=a1;
    for(int bi=0;bi<3;++bi){
      const float2* kp=&kaS[bi*64+q*8];
      v2f s1={0.f,0.f}, s2v=s1;
      int ph=0;
      #pragma unroll
      for(int ai=0;ai<8;++ai){
        v2f ka=ldv(&kp[ai]), e=ldv(&E8k[ph]);
        s1=PKFMA(ka,e,s1); s2v=PKFMA(ka,SW(e),s2v);
        ph=(ph+p)&7;
      }
      v2f dv=bc2(D3_2[bi*286+s2]);
      a1=PKFMA(dv,s1,a1); a2=PKFMA(dv,s2v,a2);
    }
    const float SC2f = 0.034722222222222224f;
    float re=(a1.x-a1.y)*SC2f, im=(a2.x+a2.y)*SC2f;
    K2H[((size_t)o*286+s2)*F1+i]=make_float2(re,im);
    K2H[((size_t)o*286+s2p)*F1+i]=make_float2(sg*re,-sg*im);
  }
}

// fused1: 8-wave wave-per-j barrier-free pipeline, packed-fp32 + radix-2.
// XH2 layout: [b][s2][i]
__global__ __launch_bounds__(512,6) void fused1(
    const float2* __restrict__ XHAT, const float2* __restrict__ K1H,
    const float* __restrict__ D1SJ, const float* __restrict__ W3H,
    const float2* __restrict__ E20, const float* __restrict__ bias1,
    const unsigned* __restrict__ zLUT, const unsigned* __restrict__ xh2LUT,
    const unsigned short* __restrict__ fhLUT, const unsigned* __restrict__ aLUT,
    float2* __restrict__ XH2){
  const int b=blockIdx.x, o=blockIdx.y, t=threadIdx.x;
  const int ln=t&63, w=t>>6;
  __shared__ __align__(16) float2 zS[1330];
  __shared__ __align__(16) float2 TWE2[400];  // [r][k] = e^{i r k th}, 20x20
  __shared__ __align__(16) float2 regA[8][200];
  __shared__ __align__(16) float2 regB[8][190];

  for(int idx=t; idx<400; idx+=512){
    int r=idx/20, c=idx%20;
    TWE2[idx]=E20[(r*c)%20];
  }
  {
    float2* st=regA[0];   // xh rows staged: [0..99]=XHAT row, [100..199]=K1H row
    if(t<100) st[t]=XHAT[b*NS1+t];
    else if(t<200) st[t]=K1H[o*NS1+(t-100)];
  }
  __syncthreads();
  {
    const float2* st=regA[0];
    for(int idx=t; idx<1330; idx+=512){
      unsigned u=zLUT[idx];
      v2f xa=ldv(&st[u&0xffff]);
      v2f kb=ldv(&st[100+(u>>16)]);
      v2f p1=xa*kb, p2=xa*SW(kb);
      zS[idx]=make_float2(p1.x+p1.y, p2.y-p2.x);   // xa*conj(kb)
    }
  }
  __syncthreads();

  const float bb1=bias1[o];
  float2* G  = regA[w];
  float*  vbF= (float*)regA[w];
  float2* Fq = regA[w];
  float*  RB = (float*)regB[w];   // Sx[0..180) Sy[180..360) T0[360..380)
  float*  Sx = RB;
  float*  Sy = RB+180;
  float*  T0f= RB+360;
  float2* U_T= regB[w];           // reuse after C
  v2f fa0={0.f,0.f}, fa1=fa0, fa2=fa0;

  // B-phase twiddle rows: n=c-9 -> row (c+11)%20
  const int BROW[19]={11,12,13,14,15,16,17,18,19,0,1,2,3,4,5,6,7,8,9};

  for(int jq=0;jq<3;++jq){
    const int j=jq*8+w;
    const bool act=(j<20);
    const float* Dg=D1SJ + (act? j*1330 : 0);
    // A: Wigner-beta contraction, half-space (181 items, lmin-sorted LUT)
    if(act) for(int idx=ln; idx<181; idx+=64){
      unsigned au=aLUT[idx];
      int zi=au&2047;
      int m=(au>>11)&15, n9=(au>>15)&31, l=(au>>20)&15;
      int L=2*l+1;
      int m2=2*m+2;
      v2f a0={0.f,0.f};
      for(; l<10; ++l){
        a0=PKFMA(ldv(&zS[zi]), bc2(Dg[zi]), a0);
        zi += L*L + 2*L + m2; L += 2;
      }
      *(v2f*)&G[m*19+n9]=a0;
    }
    WFENCE;
    // B: radix-2 split S_m(g)/S_m(g+10): 45 items (mb x g-pair) + T0 (5 items)
    if(act){
    if(ln<45){
      int mb=ln/5+1, gp=(ln%5)*2;
      const float2* Gr=&G[mb*19];
      v2f E1a={0.f,0.f},E2a=E1a,O1a=E1a,O2a=E1a;
      v2f E1b=E1a,E2b=E1a,O1b=E1a,O2b=E1a;
      #pragma unroll
      for(int c=0;c<19;++c){
        v2f gv=ldv(&Gr[c]);
        const float* er=(const float*)&TWE2[BROW[c]*20+gp];
        float4 e01=*(const float4*)er;
        v2f e0={e01.x,e01.y}, e1={e01.z,e01.w};
        if(c&1){   // c odd -> n=c-9 even -> E
          E1a=PKFMA(gv,e0,E1a); E2a=PKFMA(gv,SW(e0),E2a);
          E1b=PKFMA(gv,e1,E1b); E2b=PKFMA(gv,SW(e1),E2b);
        } else {   // n odd -> O
          O1a=PKFMA(gv,e0,O1a); O2a=PKFMA(gv,SW(e0),O2a);
          O1b=PKFMA(gv,e1,O1b); O2b=PKFMA(gv,SW(e1),O2b);
        }
      }
      int si=(mb-1)*20+gp;
      float exa=E1a.x-E1a.y, oxa=O1a.x-O1a.y;
      float eya=E2a.x+E2a.y, oya=O2a.x+O2a.y;
      float exb=E1b.x-E1b.y, oxb=O1b.x-O1b.y;
      float eyb=E2b.x+E2b.y, oyb=O2b.x+O2b.y;
      *(v2f*)&Sx[si]   =(v2f){2.f*(exa+oxa), 2.f*(exb+oxb)};
      *(v2f*)&Sx[si+10]=(v2f){2.f*(exa-oxa), 2.f*(exb-oxb)};
      *(v2f*)&Sy[si]   =(v2f){2.f*(eya+oya), 2.f*(eyb+oyb)};
      *(v2f*)&Sy[si+10]=(v2f){2.f*(eya-oya), 2.f*(eyb-oyb)};
    } else if(ln<50){
      int gt=(ln-45)*2;
      float g0x=G[9].x;
      float Ea=0.f,Eb=0.f,Oa=0.f,Ob=0.f;
      #pragma unroll
      for(int n=1;n<10;++n){
        float2 gv=G[9+n];
        const float* er=(const float*)&TWE2[n*20+gt];
        float4 e01=*(const float4*)er;
        float ra=gv.x*e01.x-gv.y*e01.y;
        float rb=gv.x*e01.z-gv.y*e01.w;
        if((n&1)==0){ Ea+=ra; Eb+=rb; } else { Oa+=ra; Ob+=rb; }
      }
      T0f[gt]   =g0x+2.f*(Ea+Oa);
      T0f[gt+1] =g0x+2.f*(Eb+Ob);
      T0f[gt+10]=g0x+2.f*(Ea-Oa);
      T0f[gt+11]=g0x+2.f*(Eb-Ob);
    }
    }
    WFENCE;
    // C: radix-2 split v(a,g)/v(a+10,g): 50 items (a=0..9 x 4-g), bias+relu
    if(act && ln<50){
      int a=ln/5, g0=(ln%5)*4;
      v2f i01={T0f[g0]+bb1, T0f[g0+1]+bb1};
      v2f i23={T0f[g0+2]+bb1, T0f[g0+3]+bb1};
      v2f P01={0.f,0.f},P23=P01,Q01=P01,Q23=P01;
      #pragma unroll
      for(int m=1;m<10;++m){
        float2 e=TWE2[a*20+m];
        v2f sx01=*(const v2f*)&Sx[(m-1)*20+g0];
        v2f sx23=*(const v2f*)&Sx[(m-1)*20+g0+2];
        v2f sy01=*(const v2f*)&Sy[(m-1)*20+g0];
        v2f sy23=*(const v2f*)&Sy[(m-1)*20+g0+2];
        if(m&1){
          Q01=PKFMA(bc2(e.x),sx01,Q01); Q01=PKFMA(bc2(-e.y),sy01,Q01);
          Q23=PKFMA(bc2(e.x),sx23,Q23); Q23=PKFMA(bc2(-e.y),sy23,Q23);
        } else {
          P01=PKFMA(bc2(e.x),sx01,P01); P01=PKFMA(bc2(-e.y),sy01,P01);
          P23=PKFMA(bc2(e.x),sx23,P23); P23=PKFMA(bc2(-e.y),sy23,P23);
        }
      }
      v2f z2={0.f,0.f};
      v2f vA01=i01+P01+Q01, vA23=i23+P23+Q23;
      v2f vB01=i01+P01-Q01, vB23=i23+P23-Q23;
      *(v2f*)&vbF[a*20+g0]       =__builtin_elementwise_max(vA01,z2);
      *(v2f*)&vbF[a*20+g0+2]     =__builtin_elementwise_max(vA23,z2);
      *(v2f*)&vbF[(a+10)*20+g0]  =__builtin_elementwise_max(vB01,z2);
      *(v2f*)&vbF[(a+10)*20+g0+2]=__builtin_elementwise_max(vB23,z2);
    }
    WFENCE;
    // D: radix-2 input split U_T[nu][a]=sum_{g<10}(v(a,g)+/-v(a,g+10))e^{-i nu g}
    if(act && ln<60){
      int a=ln/3, np=ln%3;
      int nu0=2*np, nu1=2*np+1;
      int r0=(np==0)?0:(20-2*np);
      int r1=19-2*np;
      const float* vp=&vbF[a*20];
      const float2* T0r=&TWE2[r0*20];
      const float2* T1r=&TWE2[r1*20];
      v2f u0={0.f,0.f}, u1=u0;
      #pragma unroll
      for(int g=0;g<10;++g){
        float va=vp[g], vb=vp[g+10];
        u0=PKFMA(bc2(va+vb), ldv(&T0r[g]), u0);
        u1=PKFMA(bc2(va-vb), ldv(&T1r[g]), u1);
      }
      *(v2f*)&U_T[nu0*20+a]=u0; *(v2f*)&U_T[nu1*20+a]=u1;
    }
    WFENCE;
    // E: radix-2 input split Fq(mu,nu)=sum_{a<10}(U[a]+/-U[a+10])e^{-i mu a}
    if(act && ln<61){
      int mu,nu;
      if(ln<6){ mu=ln; nu=0; } else { int q=ln-6; nu=q/11+1; mu=q%11-5; }
      int mm=(mu+20)%20;
      int rm=(20-mm)%20;
      bool modd=(mm&1);
      const float2* Ur=&U_T[nu*20];
      const float2* Er=&TWE2[rm*20];
      v2f p1={0.f,0.f}, p2=p1;
      #pragma unroll
      for(int a=0;a<10;++a){
        v2f ua=ldv(&Ur[a]), ub=ldv(&Ur[a+10]);
        v2f u = modd ? (ua-ub) : (ua+ub);
        v2f e=ldv(&Er[a]);
        p1=PKFMA(u,e,p1);
        p2=PKFMA(u,SW(e),p2);
      }
      Fq[ln]=make_float2(p1.x-p1.y, p2.x+p2.y);
    }
    WFENCE;
    // F: accumulate half-s2 with W3H into registers
    if(act){
      const float* W3r=W3H + j*NH2;
      fa0=PKFMA(bc2(W3r[ln]),    ldv(&Fq[fhLUT[ln]]),    fa0);
      fa1=PKFMA(bc2(W3r[64+ln]), ldv(&Fq[fhLUT[64+ln]]), fa1);
      if(ln<18) fa2=PKFMA(bc2(W3r[128+ln]), ldv(&Fq[fhLUT[128+ln]]), fa2);
    }
    WFENCE;
  }
  // spill register accumulators, merge 8 waves, expand half->full by conjugation
  regB[w][ln]=make_float2(fa0.x,fa0.y);
  regB[w][64+ln]=make_float2(fa1.x,fa1.y);
  if(ln<18) regB[w][128+ln]=make_float2(fa2.x,fa2.y);
  __syncthreads();
  for(int h=t; h<146; h+=512){
    unsigned u=xh2LUT[h];
    int s2=u&1023, s2p=(u>>10)&1023;
    float sg=((u>>20)&1)? -1.f : 1.f;
    float2 a0=regB[0][h], a1=regB[1][h], a2=regB[2][h], a3=regB[3][h];
    float2 a4=regB[4][h], a5=regB[5][h], a6=regB[6][h], a7=regB[7][h];
    float2 a=make_float2(a0.x+a1.x+a2.x+a3.x+a4.x+a5.x+a6.x+a7.x,
                         a0.y+a1.y+a2.y+a3.y+a4.y+a5.y+a6.y+a7.y);
    XH2[(b*286+s2 )*F1+o]=a;
    XH2[(b*286+s2p)*F1+o]=make_float2(sg*a.x, -sg*a.y);
  }
}

// fused2: cooperative z2 build (3 l-groups, 4-way i-split, compact partials),
// then wave-per-3j single-pass synthesis+integrate. LDS-dieted for 3 blocks/CU.
__global__ __launch_bounds__(256,3) void fused2(
    const float2* __restrict__ XH2, const float2* __restrict__ K2H,
    const float* __restrict__ D2SJ, const float* __restrict__ WINT,
    const float2* __restrict__ E12, const float* __restrict__ bias2,
    const unsigned* __restrict__ h2LUT, const unsigned* __restrict__ xh2LUT,
    float* __restrict__ FEAT){
  const int b=blockIdx.x, o=blockIdx.y, t=threadIdx.x;
  const int ln=t&63, w=t>>6;
  __shared__ __align__(16) float2 Xs[2420];
  __shared__ __align__(16) float2 Ks[2420];
  __shared__ float2 zpS[584];      // [iq][146] compact partials
  float2* alias=(float2*)Xs;       // reused after z-build
  float2* TWE12=alias;             // [0,144): e^{i r c th12}
  float2* z2S  =alias+1744;        // [1744,2030): after 4x400 wave regions
  float*  redS =(float*)Ks;        // Ks dead after z-build groups

  const int gb[4]={0,84,165,286};
  const int hb[4]={0,44,85,146};
  for(int grp=0; grp<3; ++grp){
    int row0=gb[grp], rows=gb[grp+1]-row0;
    {
      int cnt4=rows*10;
      const float4* xsrc=(const float4*)(XH2+(size_t)(b*286+row0)*F1);
      const float4* ksrc=(const float4*)(K2H+(size_t)(o*286+row0)*F1);
      float4* xd=(float4*)Xs; float4* kd=(float4*)Ks;
      for(int i4=t;i4<cnt4;i4+=256){
        int wb=i4&~63;
        GLOAD_LDS16(xsrc+i4, xd+wb);
        GLOAD_LDS16(ksrc+i4, kd+wb);
      }
    }
    __syncthreads();
    int nh=hb[grp+1]-hb[grp];
    for(int idx=t; idx<4*nh; idx+=256){
      int hl=idx>>2, iq=idx&3;
      int h=hb[grp]+hl;
      unsigned hu=h2LUT[h];
      int l=hu&15, mi=(hu>>4)&15, ni=(hu>>8)&15;
      int L=2*l+1;
      int xr0=(B2OFFc[l]-row0)+mi*L;
      int kr0=(B2OFFc[l]-row0)+ni*L;
      v2f p1={0.f,0.f}, p2=p1;
      for(int k=0;k<L;++k){
        const float2* xp=Xs+(xr0+k)*F1+iq*5;
        const float2* kp=Ks+(kr0+k)*F1+iq*5;
        #pragma unroll
        for(int i=0;i<5;++i){
          v2f xa=ldv(&xp[i]), kb=ldv(&kp[i]);
          p1=PKFMA(xa,kb,p1);
          p2=PKFMA(xa,SW(kb),p2);
        }
      }
      zpS[iq*146+h]=make_float2(p1.x+p1.y, p2.y-p2.x);
    }
    __syncthreads();
  }
  // merge partials (compact) + Hermitian fill into z2S (aliased into Xs)
  for(int idx=t; idx<146; idx+=256){
    unsigned xu=xh2LUT[idx];
    int s2=xu&1023, s2p=(xu>>10)&1023;
    float sg=((xu>>20)&1)? -1.f : 1.f;
    float2 a;
    a.x=zpS[idx].x+zpS[146+idx].x+zpS[292+idx].x+zpS[438+idx].x;
    a.y=zpS[idx].y+zpS[146+idx].y+zpS[292+idx].y+zpS[438+idx].y;
    z2S[s2]=a;
    z2S[s2p]=make_float2(sg*a.x,-sg*a.y);
  }
  for(int idx=t; idx<144; idx+=256){
    int r=idx/12, c=idx%12;
    TWE12[idx]=E12[(r*c)%12];
  }
  __syncthreads();

  float2* base2=alias+144+w*400;
  float2* G2_0=base2; float2* G2_1=base2+66; float2* G2_2=base2+132;
  float*  SP=(float*)(base2+198);
  float*  S2x0=SP, *S2x1=SP+60, *S2x2=SP+120;
  float*  S2y0=SP+180, *S2y1=SP+240, *S2y2=SP+300;
  float*  T02=SP+360;               // [3][12]
  float personal=0.f;
  const float b2v=bias2[o];
  const int j0=3*w, j1=3*w+1, j2=3*w+2;
  const float* Dg0=D2SJ + j0*286;
  const float* Dg1=D2SJ + j1*286;
  const float* Dg2=D2SJ + j2*286;
  const int BR12[11]={7,8,9,10,11,0,1,2,3,4,5};

  // A2: 61 half items, 3 j's
  if(ln<61){
    int m,n;
    if(ln<6){m=0;n=ln;} else {int qq=ln-6;m=qq/11+1;n=qq%11-5;}
    int an=n<0?-n:n; int l=m>an?m:an; int L=2*l+1;
    int zi=B2OFFc[l]+(m+l)*L+(n+l); int m2=2*m+2;
    v2f a0={0.f,0.f}, a1=a0, a2=a0;
    for(;l<6;++l){
      v2f zv=ldv(&z2S[zi]);
      a0=PKFMA(zv, bc2(Dg0[zi]), a0);
      a1=PKFMA(zv, bc2(Dg1[zi]), a1);
      a2=PKFMA(zv, bc2(Dg2[zi]), a2);
      zi+=L*L+2*L+m2; L+=2;
    }
    int gi=m*11+(n+5);
    *(v2f*)&G2_0[gi]=a0; *(v2f*)&G2_1[gi]=a1; *(v2f*)&G2_2[gi]=a2;
  }
  WFENCE;
  // B2: radix-2 (g,g+6) split over n-parity: 30 items + 12 T0, 3 j's
  if(ln<30){
    int m=ln/6+1, g=ln%6;
    v2f E1_0={0.f,0.f},E2_0=E1_0,O1_0=E1_0,O2_0=E1_0;
    v2f E1_1=E1_0,E2_1=E1_0,O1_1=E1_0,O2_1=E1_0;
    v2f E1_2=E1_0,E2_2=E1_0,O1_2=E1_0,O2_2=E1_0;
    #pragma unroll
    for(int c=0;c<11;++c){
      float2 ef=TWE12[BR12[c]*12+g];
      v2f e={ef.x,ef.y};
      v2f g0=ldv(&G2_0[m*11+c]), g1=ldv(&G2_1[m*11+c]), g2=ldv(&G2_2[m*11+c]);
      if(c&1){  // n=c-5 even -> E
        E1_0=PKFMA(g0,e,E1_0); E2_0=PKFMA(g0,SW(e),E2_0);
        E1_1=PKFMA(g1,e,E1_1); E2_1=PKFMA(g1,SW(e),E2_1);
        E1_2=PKFMA(g2,e,E1_2); E2_2=PKFMA(g2,SW(e),E2_2);
      } else {  // n odd -> O
        O1_0=PKFMA(g0,e,O1_0); O2_0=PKFMA(g0,SW(e),O2_0);
        O1_1=PKFMA(g1,e,O1_1); O2_1=PKFMA(g1,SW(e),O2_1);
        O1_2=PKFMA(g2,e,O1_2); O2_2=PKFMA(g2,SW(e),O2_2);
      }
    }
    int si=(m-1)*12+g;
    {
      float Ex=E1_0.x-E1_0.y, Ox=O1_0.x-O1_0.y;
      float Ey=E2_0.x+E2_0.y, Oy=O2_0.x+O2_0.y;
      S2x0[si]=2.f*(Ex+Ox); S2x0[si+6]=2.f*(Ex-Ox);
      S2y0[si]=2.f*(Ey+Oy); S2y0[si+6]=2.f*(Ey-Oy);
    }
    {
      float Ex=E1_1.x-E1_1.y, Ox=O1_1.x-O1_1.y;
      float Ey=E2_1.x+E2_1.y, Oy=O2_1.x+O2_1.y;
      S2x1[si]=2.f*(Ex+Ox); S2x1[si+6]=2.f*(Ex-Ox);
      S2y1[si]=2.f*(Ey+Oy); S2y1[si+6]=2.f*(Ey-Oy);
    }
    {
      float Ex=E1_2.x-E1_2.y, Ox=O1_2.x-O1_2.y;
      float Ey=E2_2.x+E2_2.y, Oy=O2_2.x+O2_2.y;
      S2x2[si]=2.f*(Ex+Ox); S2x2[si+6]=2.f*(Ex-Ox);
      S2y2[si]=2.f*(Ey+Oy); S2y2[si+6]=2.f*(Ey-Oy);
    }
  } else if(ln<42){
    int g=ln-30;
    float r0=G2_0[5].x, r1=G2_1[5].x, r2=G2_2[5].x;
    #pragma unroll
    for(int n=1;n<6;++n){
      float2 e=TWE12[n*12+g];
      float2 g0=G2_0[5+n], g1=G2_1[5+n], g2=G2_2[5+n];
      r0+=2.f*(g0.x*e.x-g0.y*e.y);
      r1+=2.f*(g1.x*e.x-g1.y*e.y);
      r2+=2.f*(g2.x*e.x-g2.y*e.y);
    }
    T02[g]=r0; T02[12+g]=r1; T02[24+g]=r2;
  }
  WFENCE;
  // C2: 36 items, packed g-pairs, fused relu+integrate, 3 j's
  if(ln<36){
    float w0=WINT[j0], w1=WINT[j1], w2=WINT[j2];
    int a=ln/3, g4=(ln%3)*4;
    v2f iA0={T02[g4]+b2v, T02[g4+1]+b2v},       iB0={T02[g4+2]+b2v, T02[g4+3]+b2v};
    v2f iA1={T02[12+g4]+b2v, T02[12+g4+1]+b2v}, iB1={T02[12+g4+2]+b2v, T02[12+g4+3]+b2v};
    v2f iA2={T02[24+g4]+b2v, T02[24+g4+1]+b2v}, iB2={T02[24+g4+2]+b2v, T02[24+g4+3]+b2v};
    #pragma unroll
    for(int m=1;m<6;++m){
      float2 e=TWE12[a*12+m];
      v2f ex=bc2(e.x), eny=bc2(-e.y);
      int si=(m-1)*12+g4;
      v2f sx, sy;
      sx=*(const v2f*)&S2x0[si];   sy=*(const v2f*)&S2y0[si];
      iA0=PKFMA(ex,sx,iA0); iA0=PKFMA(eny,sy,iA0);
      sx=*(const v2f*)&S2x0[si+2]; sy=*(const v2f*)&S2y0[si+2];
      iB0=PKFMA(ex,sx,iB0); iB0=PKFMA(eny,sy,iB0);
      sx=*(const v2f*)&S2x1[si];   sy=*(const v2f*)&S2y1[si];
      iA1=PKFMA(ex,sx,iA1); iA1=PKFMA(eny,sy,iA1);
      sx=*(const v2f*)&S2x1[si+2]; sy=*(const v2f*)&S2y1[si+2];
      iB1=PKFMA(ex,sx,iB1); iB1=PKFMA(eny,sy,iB1);
      sx=*(const v2f*)&S2x2[si];   sy=*(const v2f*)&S2y2[si];
      iA2=PKFMA(ex,sx,iA2); iA2=PKFMA(eny,sy,iA2);
      sx=*(const v2f*)&S2x2[si+2]; sy=*(const v2f*)&S2y2[si+2];
      iB2=PKFMA(ex,sx,iB2); iB2=PKFMA(eny,sy,iB2);
    }
    v2f z2={0.f,0.f};
    v2f rA0=__builtin_elementwise_max(iA0,z2), rB0=__builtin_elementwise_max(iB0,z2);
    v2f rA1=__builtin_elementwise_max(iA1,z2), rB1=__builtin_elementwise_max(iB1,z2);
    v2f rA2=__builtin_elementwise_max(iA2,z2), rB2=__builtin_elementwise_max(iB2,z2);
    personal += w0*(rA0.x+rA0.y+rB0.x+rB0.y)
              + w1*(rA1.x+rA1.y+rB1.x+rB1.y)
              + w2*(rA2.x+rA2.y+rB2.x+rB2.y);
  }
  redS[t]=personal;
  __syncthreads();
  for(int s=128;s>0;s>>=1){
    if(t<s) redS[t]+=redS[t+s];
    __syncthreads();
  }
  if(t==0) FEAT[b*F2+o]=redS[0];
}

__global__ void head_k(const float* __restrict__ FEAT, const float* __restrict__ w_out,
                       const float* __restrict__ b_lin, float* __restrict__ out){
  int idx=blockIdx.x*blockDim.x+threadIdx.x;
  if(idx>=BATCH*FOUT) return;
  int b=idx/FOUT, q=idx%FOUT;
  float acc=b_lin[q];
  for(int f=0;f<F2;++f) acc += FEAT[b*F2+f]*w_out[q*F2+f];
  out[idx]=acc;
}

extern "C" void kernel_launch(void* const* d_in, const int* in_sizes, int n_in,
                              void* d_out, int out_size, void* d_ws, size_t ws_size,
                              hipStream_t stream) {
  const float* x    =(const float*)d_in[0];
  const float* k1   =(const float*)d_in[1];
  const float* bias1=(const float*)d_in[2];
  const float* k2   =(const float*)d_in[3];
  const float* bias2=(const float*)d_in[4];
  const float* w_out=(const float*)d_in[5];
  const float* b_lin=(const float*)d_in[6];
  float* out=(float*)d_out;

  char* ws=(char*)d_ws;
  float*  A1   =(float* )(ws+0);        //  6000 f
  float*  D1SJ =(float* )(ws+24000);    //  26600 f
  float*  W3H  =(float* )(ws+130400);   //  2920 f
  float*  D2SJ =(float* )(ws+142080);   //  3432 f
  float*  D3_2 =(float* )(ws+155808);   //  858 f (+pad)
  float*  D3_1 =(float* )(ws+159248);   //  300 f
  float*  WINT =(float* )(ws+160448);   //  12 f
  float2* E60  =(float2*)(ws+160496);   //  60 c
  float2* E20  =(float2*)(ws+160976);   //  20 c
  float2* E12  =(float2*)(ws+161136);   //  12 c (+pad)
  unsigned* zLUT=(unsigned*)(ws+161248);//  1330 u32 (+pad)
  unsigned* xh2LUT=(unsigned*)(ws+166576); // 146 u32
  unsigned* h2LUT =(unsigned*)(ws+167160); // 146 u32
  unsigned short* fhLUT=(unsigned short*)(ws+167744); // 146 u16 (+pad)
  unsigned* aLUT =(unsigned*)(ws+168048);  // 181 u32 (+pad)
  float2* XHAT =(float2*)(ws+168784);   //  [b][100] c
  float2* K1H  =(float2*)(ws+271184);   //  [o][100] c
  float2* KA   =(float2*)(ws+287184);   //  153600 c (1.2MB)
  float2* XH2  =(float2*)(ws+1515984);  //  [b][286][20] c
  float2* K2H  =(float2*)(ws+7373264);  //  [o][286][20] c
  float*  FEAT =(float* )(ws+9203664);  //  128*40 f -> 9224144 total

  (void)in_sizes; (void)n_in; (void)out_size; (void)ws_size;

  gen_all<<<704,256,0,stream>>>(k2,A1,D1SJ,W3H,D2SJ,D3_2,D3_1,WINT,E60,E20,E12,
                                zLUT,xh2LUT,h2LUT,fhLUT,aLUT,KA);
  front_k<<<936,256,0,stream>>>(x,k1,KA,D3_2,E60,A1,D3_1,h2LUT,xh2LUT,XHAT,K1H,K2H);
  dim3 g1(BATCH,F1);
  fused1<<<g1,512,0,stream>>>(XHAT,K1H,D1SJ,W3H,E20,bias1,zLUT,xh2LUT,fhLUT,aLUT,XH2);
  dim3 g2(BATCH,F2);
  fused2<<<g2,256,0,stream>>>(XH2,K2H,D2SJ,WINT,E12,bias2,h2LUT,xh2LUT,FEAT);
  head_k<<<(BATCH*FOUT+255)/256,256,0,stream>>>(FEAT,w_out,b_lin,out);
}